// Round 2
// baseline (941.100 us; speedup 1.0000x reference)
//
#include <hip/hip_runtime.h>
#include <stdint.h>

#define N_PTS 32768
#define M_CENT 1024
#define B_SZ 4
#define NS 32
#define CAP 1024
#define NR 64
#define P_TOT (B_SZ * NS * M_CENT) /* 131072 */

// ---------------- threefry2x32 (JAX-compatible, 20 rounds) ----------------
// Implements JAX's PARTITIONABLE (foldlike) mode — default since JAX 0.4.30:
//   split(key,2)[i] = threefry2x32(key, (0, i));  bits32 = y0 ^ y1 over 64b iota.
// If validation shows wrong neighbor sets, flip to original mode (counts
// [0,1,2,3] interleaved split) at the tf_block call sites.
struct Key2 { uint32_t a, b; };

__device__ __forceinline__ uint32_t rotl32(uint32_t v, uint32_t r) {
  return (v << r) | (v >> (32u - r));
}

__device__ __forceinline__ void tf2x32(uint32_t k0, uint32_t k1,
                                       uint32_t& x0, uint32_t& x1) {
  uint32_t ks0 = k0, ks1 = k1, ks2 = k0 ^ k1 ^ 0x1BD11BDAu;
  x0 += ks0; x1 += ks1;
#define TF_ROUND(r) { x0 += x1; x1 = rotl32(x1, r); x1 ^= x0; }
  TF_ROUND(13u) TF_ROUND(15u) TF_ROUND(26u) TF_ROUND(6u)
  x0 += ks1; x1 += ks2 + 1u;
  TF_ROUND(17u) TF_ROUND(29u) TF_ROUND(16u) TF_ROUND(24u)
  x0 += ks2; x1 += ks0 + 2u;
  TF_ROUND(13u) TF_ROUND(15u) TF_ROUND(26u) TF_ROUND(6u)
  x0 += ks0; x1 += ks1 + 3u;
  TF_ROUND(17u) TF_ROUND(29u) TF_ROUND(16u) TF_ROUND(24u)
  x0 += ks1; x1 += ks2 + 4u;
  TF_ROUND(13u) TF_ROUND(15u) TF_ROUND(26u) TF_ROUND(6u)
  x0 += ks2; x1 += ks0 + 5u;
#undef TF_ROUND
}

__device__ __forceinline__ Key2 tf_block(Key2 k, uint32_t hi, uint32_t lo) {
  uint32_t x0 = hi, x1 = lo;
  tf2x32(k.a, k.b, x0, x1);
  Key2 r; r.a = x0; r.b = x1; return r;
}

// -------- permutation: bits for the 2 shuffle rounds (partitionable mode) --------
__global__ __launch_bounds__(256) void perm_bits_kernel(uint32_t* __restrict__ bits1,
                                                        uint32_t* __restrict__ bits2) {
  int j = blockIdx.x * 256 + threadIdx.x;
  Key2 root; root.a = 0u; root.b = 42u;          // jax.random.key(42)
  Key2 k1   = tf_block(root, 0u, 0u);            // split(key)[0] -> permutation key
  Key2 keyA = tf_block(k1, 0u, 0u);              // shuffle round-1 carry key
  Key2 sub1 = tf_block(k1, 0u, 1u);              // round-1 subkey
  Key2 sub2 = tf_block(keyA, 0u, 1u);            // round-2 subkey
  Key2 r1 = tf_block(sub1, 0u, (uint32_t)j);
  Key2 r2 = tf_block(sub2, 0u, (uint32_t)j);
  bits1[j] = r1.a ^ r1.b;                        // partitionable 32-bit output
  bits2[j] = r2.a ^ r2.b;
}

// Brute-force stable-sort rank: rank[j] = #{k: bits[k]<bits[j]} + #{k<j: bits[k]==bits[j]}
__global__ __launch_bounds__(256) void rank_partial_kernel(const uint32_t* __restrict__ bits,
                                                           int* __restrict__ rank,
                                                           int chunk) {
  int j = blockIdx.x * 256 + threadIdx.x;
  uint32_t my = bits[j];
  int k0 = blockIdx.y * chunk;
  int cnt = 0;
  for (int k = k0; k < k0 + chunk; ++k) {
    uint32_t v = bits[k];                        // uniform address -> scalar broadcast
    cnt += (v < my || (v == my && k < j)) ? 1 : 0;
  }
  atomicAdd(&rank[j], cnt);
}

__global__ __launch_bounds__(256) void scatter1_kernel(const int* __restrict__ rank,
                                                       int* __restrict__ xmid) {
  int j = blockIdx.x * 256 + threadIdx.x;
  xmid[rank[j]] = j;                             // round 1: values = arange
}

__global__ __launch_bounds__(256) void scatter2_kernel(const int* __restrict__ rank,
                                                       const int* __restrict__ xmid,
                                                       int* __restrict__ xfin) {
  int p = blockIdx.x * 256 + threadIdx.x;
  xfin[rank[p]] = xmid[p];                       // round 2 permutes round-1 result
}

// -------- neighbor selection: one block per (b, m) center --------
__global__ __launch_bounds__(256) void select_kernel(
    const float* __restrict__ theta, const float* __restrict__ phi,
    const int* __restrict__ cent, int* __restrict__ idx_buf,
    float* __restrict__ out_ct, float* __restrict__ out_cp) {
  __shared__ int cnt;
  __shared__ float cs[CAP];
  __shared__ int cn[CAP];
  __shared__ int sel[NS];
  __shared__ float wb[4];
  __shared__ int wbn[4];
  __shared__ int wbi[4];

  int bm = blockIdx.x;
  int b = bm >> 10, m = bm & 1023;
  int tid = threadIdx.x;
  int ci = cent[m];
  float ctv = theta[b * N_PTS + ci];
  float cpv = phi[b * N_PTS + ci];
  if (tid == 0) { cnt = 0; out_ct[bm] = ctv; out_cp[bm] = cpv; }
  __syncthreads();

  Key2 root; root.a = 0u; root.b = 42u;
  Key2 k2 = tf_block(root, 0u, 1u);              // split(key)[1] -> scores key
  const float* th = theta + (size_t)b * N_PTS;
  const float* ph = phi + (size_t)b * N_PTS;
  uint32_t flat_base = (uint32_t)bm * (uint32_t)N_PTS;

  // vectorized scan: 16B/lane coalesced loads, 32 iterations per thread
  for (int base = tid * 4; base < N_PTS; base += 1024) {
    float4 tv = *reinterpret_cast<const float4*>(th + base);
    float4 pv = *reinterpret_cast<const float4*>(ph + base);
#pragma unroll
    for (int u = 0; u < 4; ++u) {
      float t = (u == 0) ? tv.x : (u == 1) ? tv.y : (u == 2) ? tv.z : tv.w;
      float p = (u == 0) ? pv.x : (u == 1) ? pv.y : (u == 2) ? pv.z : pv.w;
      // match XLA's uncontracted f32 elementwise chain exactly
      float dx = __fsub_rn(t, ctv);
      float dy = __fsub_rn(p, cpv);
      float d2 = __fadd_rn(__fmul_rn(dx, dx), __fmul_rn(dy, dy));
      float d = __fsqrt_rn(d2);
      if (d <= 0.1f) {
        int n = base + u;
        Key2 r = tf_block(k2, 0u, flat_base + (uint32_t)n);
        uint32_t bits = r.a ^ r.b;
        float sc = __uint_as_float(0x3f800000u | (bits >> 9)) - 1.0f; // uniform [0,1)
        int pp = atomicAdd(&cnt, 1);
        if (pp < CAP) { cs[pp] = sc; cn[pp] = n; }
      }
    }
  }
  __syncthreads();
  int K = min(cnt, CAP);

  // 32 rounds of lex-min (score, n) == stable top_k(-scores) incl. tie-breaks
  for (int r = 0; r < NS; ++r) {
    float best = 3.0e38f;
    int bn = 0x7fffffff, bi = -1;
    for (int i = tid; i < K; i += 256) {
      float s = cs[i]; int nn = cn[i];
      if (s < best || (s == best && nn < bn)) { best = s; bn = nn; bi = i; }
    }
    for (int off = 32; off > 0; off >>= 1) {
      float os = __shfl_xor(best, off);
      int on = __shfl_xor(bn, off);
      int oi = __shfl_xor(bi, off);
      if (os < best || (os == best && on < bn)) { best = os; bn = on; bi = oi; }
    }
    if ((tid & 63) == 0) { int w = tid >> 6; wb[w] = best; wbn[w] = bn; wbi[w] = bi; }
    __syncthreads();
    if (tid == 0) {
      for (int w = 1; w < 4; ++w)
        if (wb[w] < best || (wb[w] == best && wbn[w] < bn)) { best = wb[w]; bn = wbn[w]; bi = wbi[w]; }
      sel[r] = (bi >= 0) ? bn : sel[0];          // pad with argmin (== idx[...,:1])
      if (bi >= 0) cs[bi] = 3.0e38f;
    }
    __syncthreads();
  }
  if (tid < NS) idx_buf[bm * NS + tid] = sel[tid];
}

// -------- MLP helpers --------
template <int CI, int CO, bool RELU>
__device__ __forceinline__ void layer_fw(const float* __restrict__ W,
                                         const float* __restrict__ bv,
                                         const float* __restrict__ Xin,
                                         float* __restrict__ Y, int tid) {
  for (int v = tid; v < CO * NS; v += 256) {
    int o = v >> 5, s = v & (NS - 1);
    float acc = bv[o];
    const float* wr = W + o * CI;
#pragma unroll
    for (int c = 0; c < CI; ++c) acc = fmaf(wr[c], Xin[c * NS + s], acc);
    if (RELU) acc = fmaxf(acc, 0.0f);
    Y[o * NS + s] = acc;
  }
}

template <int CO>
__device__ __forceinline__ void accum_stats(const float* __restrict__ Y,
                                            double* __restrict__ S, int tid, int bid) {
  if (tid < CO) {
    double s1 = 0.0, s2 = 0.0;
#pragma unroll
    for (int s = 0; s < NS; ++s) {
      double v = (double)Y[tid * NS + s];
      s1 += v; s2 += v * v;
    }
    double* base = S + (size_t)(bid & (NR - 1)) * (2 * CO);
    atomicAdd(base + tid, s1);
    atomicAdd(base + CO + tid, s2);
  }
}

__device__ __forceinline__ void gather_x1(const int* __restrict__ idx_buf,
                                          const float* __restrict__ feat,
                                          int bm, int b, int* idxs, float* X1, int tid) {
  if (tid < NS) idxs[tid] = idx_buf[bm * NS + tid];
  __syncthreads();
  for (int v = tid; v < 16 * NS; v += 256) {
    int c = v >> 5, s = v & (NS - 1);
    X1[v] = feat[(size_t)(b * 16 + c) * N_PTS + idxs[s]];
  }
}

__global__ __launch_bounds__(256) void pass_stats1_kernel(
    const float* __restrict__ feat, const int* __restrict__ idx_buf,
    const float* __restrict__ w0, const float* __restrict__ b0,
    double* __restrict__ stats) {
  __shared__ int idxs[NS];
  __shared__ float X1[16 * NS];
  __shared__ float Y[32 * NS];
  int bm = blockIdx.x, tid = threadIdx.x, b = bm >> 10;
  gather_x1(idx_buf, feat, bm, b, idxs, X1, tid);
  __syncthreads();
  layer_fw<16, 32, false>(w0, b0, X1, Y, tid);
  __syncthreads();
  accum_stats<32>(Y, stats, tid, bm);
}

__global__ __launch_bounds__(256) void pass_stats2_kernel(
    const float* __restrict__ feat, const int* __restrict__ idx_buf,
    const float* __restrict__ we1, const float* __restrict__ be1,
    const float* __restrict__ w1, const float* __restrict__ b1,
    double* __restrict__ stats) {
  __shared__ int idxs[NS];
  __shared__ float X1[16 * NS];
  __shared__ float X2[32 * NS];
  __shared__ float Y[32 * NS];
  int bm = blockIdx.x, tid = threadIdx.x, b = bm >> 10;
  gather_x1(idx_buf, feat, bm, b, idxs, X1, tid);
  __syncthreads();
  layer_fw<16, 32, true>(we1, be1, X1, X2, tid);
  __syncthreads();
  layer_fw<32, 32, false>(w1, b1, X2, Y, tid);
  __syncthreads();
  accum_stats<32>(Y, stats, tid, bm);
}

__global__ __launch_bounds__(256) void pass_stats3_kernel(
    const float* __restrict__ feat, const int* __restrict__ idx_buf,
    const float* __restrict__ we1, const float* __restrict__ be1,
    const float* __restrict__ we2, const float* __restrict__ be2,
    const float* __restrict__ w2, const float* __restrict__ b2,
    double* __restrict__ stats) {
  __shared__ int idxs[NS];
  __shared__ float X1[16 * NS];
  __shared__ float X2[32 * NS];
  __shared__ float X3[32 * NS];
  __shared__ float Y[64 * NS];
  int bm = blockIdx.x, tid = threadIdx.x, b = bm >> 10;
  gather_x1(idx_buf, feat, bm, b, idxs, X1, tid);
  __syncthreads();
  layer_fw<16, 32, true>(we1, be1, X1, X2, tid);
  __syncthreads();
  layer_fw<32, 32, true>(we2, be2, X2, X3, tid);
  __syncthreads();
  layer_fw<32, 64, false>(w2, b2, X3, Y, tid);
  __syncthreads();
  accum_stats<64>(Y, stats, tid, bm);
}

__global__ __launch_bounds__(256) void pass_final_kernel(
    const float* __restrict__ feat, const int* __restrict__ idx_buf,
    const float* __restrict__ we1, const float* __restrict__ be1,
    const float* __restrict__ we2, const float* __restrict__ be2,
    const float* __restrict__ we3, const float* __restrict__ be3,
    float* __restrict__ out_ft) {
  __shared__ int idxs[NS];
  __shared__ float X1[16 * NS];
  __shared__ float X2[32 * NS];
  __shared__ float X3[32 * NS];
  __shared__ float Y[64 * NS];
  int bm = blockIdx.x, tid = threadIdx.x, b = bm >> 10, m = bm & 1023;
  gather_x1(idx_buf, feat, bm, b, idxs, X1, tid);
  __syncthreads();
  layer_fw<16, 32, true>(we1, be1, X1, X2, tid);
  __syncthreads();
  layer_fw<32, 32, true>(we2, be2, X2, X3, tid);
  __syncthreads();
  layer_fw<32, 64, true>(we3, be3, X3, Y, tid);
  __syncthreads();
  if (tid < 64) {
    float mx = Y[tid * NS];
#pragma unroll
    for (int s = 1; s < NS; ++s) mx = fmaxf(mx, Y[tid * NS + s]);
    out_ft[(size_t)(b * 64 + tid) * M_CENT + m] = mx;
  }
}

// fixup: fold BN(mean/var of pre-activation) into effective W' = a*W, b' = (b-mu)*a + beta
template <int CI, int CO>
__global__ void fixup_kernel(const double* __restrict__ S,
                             const float* __restrict__ W, const float* __restrict__ bv,
                             const float* __restrict__ g, const float* __restrict__ be,
                             float* __restrict__ Weff, float* __restrict__ beff) {
  int o = threadIdx.x;
  if (o >= CO) return;
  double s1 = 0.0, s2 = 0.0;
  for (int r = 0; r < NR; ++r) {
    s1 += S[r * 2 * CO + o];
    s2 += S[r * 2 * CO + CO + o];
  }
  const double P = (double)P_TOT;
  double mu = s1 / P;
  double var = s2 / P - mu * mu;
  double a = (double)g[o] / sqrt(var + 1e-5);
  for (int c = 0; c < CI; ++c) Weff[o * CI + c] = (float)(a * (double)W[o * CI + c]);
  beff[o] = (float)(((double)bv[o] - mu) * a + (double)be[o]);
}

extern "C" void kernel_launch(void* const* d_in, const int* in_sizes, int n_in,
                              void* d_out, int out_size, void* d_ws, size_t ws_size,
                              hipStream_t stream) {
  (void)in_sizes; (void)n_in; (void)out_size; (void)ws_size;
  const float* theta = (const float*)d_in[0];
  const float* phi   = (const float*)d_in[1];
  const float* feat  = (const float*)d_in[2];
  const float* w0 = (const float*)d_in[3];
  const float* b0 = (const float*)d_in[4];
  const float* g0 = (const float*)d_in[5];
  const float* be0 = (const float*)d_in[6];
  const float* w1 = (const float*)d_in[7];
  const float* b1 = (const float*)d_in[8];
  const float* g1 = (const float*)d_in[9];
  const float* be1 = (const float*)d_in[10];
  const float* w2 = (const float*)d_in[11];
  const float* b2 = (const float*)d_in[12];
  const float* g2 = (const float*)d_in[13];
  const float* be2 = (const float*)d_in[14];

  float* out = (float*)d_out;
  float* out_ct = out;
  float* out_cp = out + B_SZ * M_CENT;
  float* out_ft = out + 2 * B_SZ * M_CENT;

  char* ws = (char*)d_ws;
  uint32_t* bits1 = (uint32_t*)(ws + 0);
  uint32_t* bits2 = (uint32_t*)(ws + 131072);
  int* rank1 = (int*)(ws + 262144);
  int* rank2 = (int*)(ws + 393216);
  int* xmid  = (int*)(ws + 524288);
  int* xfin  = (int*)(ws + 655360);      // xfin[0:1024] == cent_idx
  int* idx_buf = (int*)(ws + 786432);    // [4096][32]
  double* stats1 = (double*)(ws + 1310720);              // NR*2*32*8 = 32KB
  double* stats2 = (double*)(ws + 1310720 + 32768);      // 32KB
  double* stats3 = (double*)(ws + 1310720 + 65536);      // NR*2*64*8 = 64KB
  float* weff1 = (float*)(ws + 1310720 + 131072);
  float* beff1 = weff1 + 32 * 16;
  float* weff2 = beff1 + 32;
  float* beff2 = weff2 + 32 * 32;
  float* weff3 = beff2 + 32;
  float* beff3 = weff3 + 64 * 32;

  hipMemsetAsync(ws + 262144, 0, 262144, stream);          // rank1, rank2
  hipMemsetAsync(ws + 1310720, 0, 131072, stream);         // stats1..3

  perm_bits_kernel<<<128, 256, 0, stream>>>(bits1, bits2);
  rank_partial_kernel<<<dim3(128, 16), 256, 0, stream>>>(bits1, rank1, 2048);
  rank_partial_kernel<<<dim3(128, 16), 256, 0, stream>>>(bits2, rank2, 2048);
  scatter1_kernel<<<128, 256, 0, stream>>>(rank1, xmid);
  scatter2_kernel<<<128, 256, 0, stream>>>(rank2, xmid, xfin);

  select_kernel<<<B_SZ * M_CENT, 256, 0, stream>>>(theta, phi, xfin, idx_buf,
                                                   out_ct, out_cp);

  pass_stats1_kernel<<<B_SZ * M_CENT, 256, 0, stream>>>(feat, idx_buf, w0, b0, stats1);
  fixup_kernel<16, 32><<<1, 64, 0, stream>>>(stats1, w0, b0, g0, be0, weff1, beff1);
  pass_stats2_kernel<<<B_SZ * M_CENT, 256, 0, stream>>>(feat, idx_buf, weff1, beff1,
                                                        w1, b1, stats2);
  fixup_kernel<32, 32><<<1, 64, 0, stream>>>(stats2, w1, b1, g1, be1, weff2, beff2);
  pass_stats3_kernel<<<B_SZ * M_CENT, 256, 0, stream>>>(feat, idx_buf, weff1, beff1,
                                                        weff2, beff2, w2, b2, stats3);
  fixup_kernel<32, 64><<<1, 64, 0, stream>>>(stats3, w2, b2, g2, be2, weff3, beff3);
  pass_final_kernel<<<B_SZ * M_CENT, 256, 0, stream>>>(feat, idx_buf, weff1, beff1,
                                                       weff2, beff2, weff3, beff3, out_ft);
}

// Round 3
// 483.345 us; speedup vs baseline: 1.9471x; 1.9471x over previous
//
#include <hip/hip_runtime.h>
#include <stdint.h>

#define N_PTS 32768
#define M_CENT 1024
#define B_SZ 4
#define NS 32
#define CAP 1024
#define NR 64
#define NB 65536 /* 16-bit buckets */
#define P_TOT (B_SZ * NS * M_CENT) /* 131072 */

// ---------------- threefry2x32 (JAX-compatible, 20 rounds) ----------------
// Partitionable (foldlike) mode — default since JAX 0.4.30.
struct Key2 { uint32_t a, b; };

__device__ __forceinline__ uint32_t rotl32(uint32_t v, uint32_t r) {
  return (v << r) | (v >> (32u - r));
}

__device__ __forceinline__ void tf2x32(uint32_t k0, uint32_t k1,
                                       uint32_t& x0, uint32_t& x1) {
  uint32_t ks0 = k0, ks1 = k1, ks2 = k0 ^ k1 ^ 0x1BD11BDAu;
  x0 += ks0; x1 += ks1;
#define TF_ROUND(r) { x0 += x1; x1 = rotl32(x1, r); x1 ^= x0; }
  TF_ROUND(13u) TF_ROUND(15u) TF_ROUND(26u) TF_ROUND(6u)
  x0 += ks1; x1 += ks2 + 1u;
  TF_ROUND(17u) TF_ROUND(29u) TF_ROUND(16u) TF_ROUND(24u)
  x0 += ks2; x1 += ks0 + 2u;
  TF_ROUND(13u) TF_ROUND(15u) TF_ROUND(26u) TF_ROUND(6u)
  x0 += ks0; x1 += ks1 + 3u;
  TF_ROUND(17u) TF_ROUND(29u) TF_ROUND(16u) TF_ROUND(24u)
  x0 += ks1; x1 += ks2 + 4u;
  TF_ROUND(13u) TF_ROUND(15u) TF_ROUND(26u) TF_ROUND(6u)
  x0 += ks2; x1 += ks0 + 5u;
#undef TF_ROUND
}

__device__ __forceinline__ Key2 tf_block(Key2 k, uint32_t hi, uint32_t lo) {
  uint32_t x0 = hi, x1 = lo;
  tf2x32(k.a, k.b, x0, x1);
  Key2 r; r.a = x0; r.b = x1; return r;
}

// -------- permutation bits for the 2 shuffle rounds --------
__global__ __launch_bounds__(256) void perm_bits_kernel(uint32_t* __restrict__ bits1,
                                                        uint32_t* __restrict__ bits2) {
  int j = blockIdx.x * 256 + threadIdx.x;
  Key2 root; root.a = 0u; root.b = 42u;          // jax.random.key(42)
  Key2 k1   = tf_block(root, 0u, 0u);            // split(key)[0] -> permutation key
  Key2 keyA = tf_block(k1, 0u, 0u);              // shuffle round-1 carry key
  Key2 sub1 = tf_block(k1, 0u, 1u);              // round-1 subkey
  Key2 sub2 = tf_block(keyA, 0u, 1u);            // round-2 subkey
  Key2 r1 = tf_block(sub1, 0u, (uint32_t)j);
  Key2 r2 = tf_block(sub2, 0u, (uint32_t)j);
  bits1[j] = r1.a ^ r1.b;
  bits2[j] = r2.a ^ r2.b;
}

// -------- counting-sort rank (O(N)): 16-bit bucket histogram --------
__global__ __launch_bounds__(256) void hist_kernel(const uint32_t* __restrict__ bits1,
                                                   const uint32_t* __restrict__ bits2,
                                                   int* __restrict__ hist1,
                                                   int* __restrict__ hist2) {
  int j = blockIdx.x * 256 + threadIdx.x;
  atomicAdd(&hist1[bits1[j] >> 16], 1);
  atomicAdd(&hist2[bits2[j] >> 16], 1);
}

// group sums + exclusive scan over 256 groups (one block per round)
__global__ __launch_bounds__(256) void gsum_scan_kernel(const int* __restrict__ hist1,
                                                        const int* __restrict__ hist2,
                                                        int* __restrict__ gbase1,
                                                        int* __restrict__ gbase2) {
  __shared__ int s[256];
  const int* hist = blockIdx.x == 0 ? hist1 : hist2;
  int* gbase = blockIdx.x == 0 ? gbase1 : gbase2;
  int g = threadIdx.x;
  int sum = 0;
  for (int i = 0; i < 256; ++i) sum += hist[g * 256 + i];
  s[g] = sum;
  __syncthreads();
  if (g == 0) {
    int run = 0;
    for (int i = 0; i < 256; ++i) { int t = s[i]; s[i] = run; run += t; }
  }
  __syncthreads();
  gbase[g] = s[g];
}

// per-group exclusive scan -> bucket prefix; also init cursor copy
__global__ __launch_bounds__(256) void bucket_scan_kernel(const int* __restrict__ hist1,
                                                          const int* __restrict__ hist2,
                                                          const int* __restrict__ gbase1,
                                                          const int* __restrict__ gbase2,
                                                          int* __restrict__ prefix1,
                                                          int* __restrict__ prefix2,
                                                          int* __restrict__ cursor1,
                                                          int* __restrict__ cursor2) {
  __shared__ int s[256];
  const int* hist = blockIdx.y == 0 ? hist1 : hist2;
  const int* gbase = blockIdx.y == 0 ? gbase1 : gbase2;
  int* prefix = blockIdx.y == 0 ? prefix1 : prefix2;
  int* cursor = blockIdx.y == 0 ? cursor1 : cursor2;
  int g = blockIdx.x, t = threadIdx.x;
  int idx = g * 256 + t;
  int orig = hist[idx];
  s[t] = orig;
  __syncthreads();
  for (int off = 1; off < 256; off <<= 1) {
    int v = (t >= off) ? s[t - off] : 0;
    __syncthreads();
    s[t] += v;
    __syncthreads();
  }
  int pref = gbase[g] + s[t] - orig;   // exclusive
  prefix[idx] = pref;
  cursor[idx] = pref;
}

// scatter indices into bucket-sorted order (within-bucket order arbitrary)
__global__ __launch_bounds__(256) void bucket_scatter_kernel(const uint32_t* __restrict__ bits1,
                                                             const uint32_t* __restrict__ bits2,
                                                             int* __restrict__ cursor1,
                                                             int* __restrict__ cursor2,
                                                             int* __restrict__ sorted1,
                                                             int* __restrict__ sorted2) {
  int j = blockIdx.x * 256 + threadIdx.x;
  int p1 = atomicAdd(&cursor1[bits1[j] >> 16], 1);
  sorted1[p1] = j;
  int p2 = atomicAdd(&cursor2[bits2[j] >> 16], 1);
  sorted2[p2] = j;
}

__device__ __forceinline__ int exact_rank(const uint32_t* __restrict__ bits,
                                          const int* __restrict__ prefix,
                                          const int* __restrict__ hist,
                                          const int* __restrict__ sorted, int j) {
  uint32_t my = bits[j];
  int b = (int)(my >> 16);
  int start = prefix[b];
  int cnt = hist[b];
  int r = start;
  for (int i = 0; i < cnt; ++i) {
    int m = sorted[start + i];
    uint32_t vb = bits[m];
    if (vb < my || (vb == my && m < j)) ++r;   // stable: (bits, idx) lex
  }
  return r;
}

// round-1 rank scatters xmid directly; round-2 rank stored for scatter2
__global__ __launch_bounds__(256) void rank_scatter1_kernel(
    const uint32_t* __restrict__ bits1, const uint32_t* __restrict__ bits2,
    const int* __restrict__ prefix1, const int* __restrict__ prefix2,
    const int* __restrict__ hist1, const int* __restrict__ hist2,
    const int* __restrict__ sorted1, const int* __restrict__ sorted2,
    int* __restrict__ xmid, int* __restrict__ rank2) {
  int j = blockIdx.x * 256 + threadIdx.x;
  int r1 = exact_rank(bits1, prefix1, hist1, sorted1, j);
  xmid[r1] = j;                                  // round 1: values = arange
  rank2[j] = exact_rank(bits2, prefix2, hist2, sorted2, j);
}

__global__ __launch_bounds__(256) void scatter2_kernel(const int* __restrict__ rank2,
                                                       const int* __restrict__ xmid,
                                                       int* __restrict__ xfin) {
  int p = blockIdx.x * 256 + threadIdx.x;
  xfin[rank2[p]] = xmid[p];                      // round 2 permutes round-1 result
}

// -------- neighbor selection: one block per (b, m) center --------
__global__ __launch_bounds__(256) void select_kernel(
    const float* __restrict__ theta, const float* __restrict__ phi,
    const int* __restrict__ cent, int* __restrict__ idx_buf,
    float* __restrict__ out_ct, float* __restrict__ out_cp) {
  __shared__ int cnt;
  __shared__ float cs[CAP];
  __shared__ int cn[CAP];
  __shared__ int sel[NS];
  __shared__ float wb[4];
  __shared__ int wbn[4];
  __shared__ int wbi[4];

  int bm = blockIdx.x;
  int b = bm >> 10, m = bm & 1023;
  int tid = threadIdx.x;
  int ci = cent[m];
  float ctv = theta[b * N_PTS + ci];
  float cpv = phi[b * N_PTS + ci];
  if (tid == 0) { cnt = 0; out_ct[bm] = ctv; out_cp[bm] = cpv; }
  __syncthreads();

  Key2 root; root.a = 0u; root.b = 42u;
  Key2 k2 = tf_block(root, 0u, 1u);              // split(key)[1] -> scores key
  const float* th = theta + (size_t)b * N_PTS;
  const float* ph = phi + (size_t)b * N_PTS;
  uint32_t flat_base = (uint32_t)bm * (uint32_t)N_PTS;

  for (int base = tid * 4; base < N_PTS; base += 1024) {
    float4 tv = *reinterpret_cast<const float4*>(th + base);
    float4 pv = *reinterpret_cast<const float4*>(ph + base);
#pragma unroll
    for (int u = 0; u < 4; ++u) {
      float t = (u == 0) ? tv.x : (u == 1) ? tv.y : (u == 2) ? tv.z : tv.w;
      float p = (u == 0) ? pv.x : (u == 1) ? pv.y : (u == 2) ? pv.z : pv.w;
      // match XLA's uncontracted f32 elementwise chain exactly
      float dx = __fsub_rn(t, ctv);
      float dy = __fsub_rn(p, cpv);
      float d2 = __fadd_rn(__fmul_rn(dx, dx), __fmul_rn(dy, dy));
      float d = __fsqrt_rn(d2);
      if (d <= 0.1f) {
        int n = base + u;
        Key2 r = tf_block(k2, 0u, flat_base + (uint32_t)n);
        uint32_t bits = r.a ^ r.b;
        float sc = __uint_as_float(0x3f800000u | (bits >> 9)) - 1.0f; // uniform [0,1)
        int pp = atomicAdd(&cnt, 1);
        if (pp < CAP) { cs[pp] = sc; cn[pp] = n; }
      }
    }
  }
  __syncthreads();
  int K = min(cnt, CAP);

  // 32 rounds of lex-min (score, n) == stable top_k(-scores) incl. tie-breaks
  for (int r = 0; r < NS; ++r) {
    float best = 3.0e38f;
    int bn = 0x7fffffff, bi = -1;
    for (int i = tid; i < K; i += 256) {
      float s = cs[i]; int nn = cn[i];
      if (s < best || (s == best && nn < bn)) { best = s; bn = nn; bi = i; }
    }
    for (int off = 32; off > 0; off >>= 1) {
      float os = __shfl_xor(best, off);
      int on = __shfl_xor(bn, off);
      int oi = __shfl_xor(bi, off);
      if (os < best || (os == best && on < bn)) { best = os; bn = on; bi = oi; }
    }
    if ((tid & 63) == 0) { int w = tid >> 6; wb[w] = best; wbn[w] = bn; wbi[w] = bi; }
    __syncthreads();
    if (tid == 0) {
      for (int w = 1; w < 4; ++w)
        if (wb[w] < best || (wb[w] == best && wbn[w] < bn)) { best = wb[w]; bn = wbn[w]; bi = wbi[w]; }
      sel[r] = (bi >= 0) ? bn : sel[0];          // pad with argmin (== idx[...,:1])
      if (bi >= 0) cs[bi] = 3.0e38f;
    }
    __syncthreads();
  }
  if (tid < NS) idx_buf[bm * NS + tid] = sel[tid];
}

// -------- MLP helpers --------
template <int CI, int CO, bool RELU>
__device__ __forceinline__ void layer_fw(const float* __restrict__ W,
                                         const float* __restrict__ bv,
                                         const float* __restrict__ Xin,
                                         float* __restrict__ Y, int tid) {
  for (int v = tid; v < CO * NS; v += 256) {
    int o = v >> 5, s = v & (NS - 1);
    float acc = bv[o];
    const float* wr = W + o * CI;
#pragma unroll
    for (int c = 0; c < CI; ++c) acc = fmaf(wr[c], Xin[c * NS + s], acc);
    if (RELU) acc = fmaxf(acc, 0.0f);
    Y[o * NS + s] = acc;
  }
}

template <int CO>
__device__ __forceinline__ void accum_stats(const float* __restrict__ Y,
                                            double* __restrict__ S, int tid, int bid) {
  if (tid < CO) {
    double s1 = 0.0, s2 = 0.0;
#pragma unroll
    for (int s = 0; s < NS; ++s) {
      double v = (double)Y[tid * NS + s];
      s1 += v; s2 += v * v;
    }
    double* base = S + (size_t)(bid & (NR - 1)) * (2 * CO);
    atomicAdd(base + tid, s1);
    atomicAdd(base + CO + tid, s2);
  }
}

__device__ __forceinline__ void gather_x1(const int* __restrict__ idx_buf,
                                          const float* __restrict__ feat,
                                          int bm, int b, int* idxs, float* X1, int tid) {
  if (tid < NS) idxs[tid] = idx_buf[bm * NS + tid];
  __syncthreads();
  for (int v = tid; v < 16 * NS; v += 256) {
    int c = v >> 5, s = v & (NS - 1);
    X1[v] = feat[(size_t)(b * 16 + c) * N_PTS + idxs[s]];
  }
}

__global__ __launch_bounds__(256) void pass_stats1_kernel(
    const float* __restrict__ feat, const int* __restrict__ idx_buf,
    const float* __restrict__ w0, const float* __restrict__ b0,
    double* __restrict__ stats) {
  __shared__ int idxs[NS];
  __shared__ float X1[16 * NS];
  __shared__ float Y[32 * NS];
  int bm = blockIdx.x, tid = threadIdx.x, b = bm >> 10;
  gather_x1(idx_buf, feat, bm, b, idxs, X1, tid);
  __syncthreads();
  layer_fw<16, 32, false>(w0, b0, X1, Y, tid);
  __syncthreads();
  accum_stats<32>(Y, stats, tid, bm);
}

__global__ __launch_bounds__(256) void pass_stats2_kernel(
    const float* __restrict__ feat, const int* __restrict__ idx_buf,
    const float* __restrict__ we1, const float* __restrict__ be1,
    const float* __restrict__ w1, const float* __restrict__ b1,
    double* __restrict__ stats) {
  __shared__ int idxs[NS];
  __shared__ float X1[16 * NS];
  __shared__ float X2[32 * NS];
  __shared__ float Y[32 * NS];
  int bm = blockIdx.x, tid = threadIdx.x, b = bm >> 10;
  gather_x1(idx_buf, feat, bm, b, idxs, X1, tid);
  __syncthreads();
  layer_fw<16, 32, true>(we1, be1, X1, X2, tid);
  __syncthreads();
  layer_fw<32, 32, false>(w1, b1, X2, Y, tid);
  __syncthreads();
  accum_stats<32>(Y, stats, tid, bm);
}

__global__ __launch_bounds__(256) void pass_stats3_kernel(
    const float* __restrict__ feat, const int* __restrict__ idx_buf,
    const float* __restrict__ we1, const float* __restrict__ be1,
    const float* __restrict__ we2, const float* __restrict__ be2,
    const float* __restrict__ w2, const float* __restrict__ b2,
    double* __restrict__ stats) {
  __shared__ int idxs[NS];
  __shared__ float X1[16 * NS];
  __shared__ float X2[32 * NS];
  __shared__ float X3[32 * NS];
  __shared__ float Y[64 * NS];
  int bm = blockIdx.x, tid = threadIdx.x, b = bm >> 10;
  gather_x1(idx_buf, feat, bm, b, idxs, X1, tid);
  __syncthreads();
  layer_fw<16, 32, true>(we1, be1, X1, X2, tid);
  __syncthreads();
  layer_fw<32, 32, true>(we2, be2, X2, X3, tid);
  __syncthreads();
  layer_fw<32, 64, false>(w2, b2, X3, Y, tid);
  __syncthreads();
  accum_stats<64>(Y, stats, tid, bm);
}

__global__ __launch_bounds__(256) void pass_final_kernel(
    const float* __restrict__ feat, const int* __restrict__ idx_buf,
    const float* __restrict__ we1, const float* __restrict__ be1,
    const float* __restrict__ we2, const float* __restrict__ be2,
    const float* __restrict__ we3, const float* __restrict__ be3,
    float* __restrict__ out_ft) {
  __shared__ int idxs[NS];
  __shared__ float X1[16 * NS];
  __shared__ float X2[32 * NS];
  __shared__ float X3[32 * NS];
  __shared__ float Y[64 * NS];
  int bm = blockIdx.x, tid = threadIdx.x, b = bm >> 10, m = bm & 1023;
  gather_x1(idx_buf, feat, bm, b, idxs, X1, tid);
  __syncthreads();
  layer_fw<16, 32, true>(we1, be1, X1, X2, tid);
  __syncthreads();
  layer_fw<32, 32, true>(we2, be2, X2, X3, tid);
  __syncthreads();
  layer_fw<32, 64, true>(we3, be3, X3, Y, tid);
  __syncthreads();
  if (tid < 64) {
    float mx = Y[tid * NS];
#pragma unroll
    for (int s = 1; s < NS; ++s) mx = fmaxf(mx, Y[tid * NS + s]);
    out_ft[(size_t)(b * 64 + tid) * M_CENT + m] = mx;
  }
}

// fixup: fold BN(mean/var of pre-activation) into effective W' = a*W, b' = (b-mu)*a + beta
template <int CI, int CO>
__global__ void fixup_kernel(const double* __restrict__ S,
                             const float* __restrict__ W, const float* __restrict__ bv,
                             const float* __restrict__ g, const float* __restrict__ be,
                             float* __restrict__ Weff, float* __restrict__ beff) {
  int o = threadIdx.x;
  if (o >= CO) return;
  double s1 = 0.0, s2 = 0.0;
  for (int r = 0; r < NR; ++r) {
    s1 += S[r * 2 * CO + o];
    s2 += S[r * 2 * CO + CO + o];
  }
  const double P = (double)P_TOT;
  double mu = s1 / P;
  double var = s2 / P - mu * mu;
  double a = (double)g[o] / sqrt(var + 1e-5);
  for (int c = 0; c < CI; ++c) Weff[o * CI + c] = (float)(a * (double)W[o * CI + c]);
  beff[o] = (float)(((double)bv[o] - mu) * a + (double)be[o]);
}

extern "C" void kernel_launch(void* const* d_in, const int* in_sizes, int n_in,
                              void* d_out, int out_size, void* d_ws, size_t ws_size,
                              hipStream_t stream) {
  (void)in_sizes; (void)n_in; (void)out_size; (void)ws_size;
  const float* theta = (const float*)d_in[0];
  const float* phi   = (const float*)d_in[1];
  const float* feat  = (const float*)d_in[2];
  const float* w0 = (const float*)d_in[3];
  const float* b0 = (const float*)d_in[4];
  const float* g0 = (const float*)d_in[5];
  const float* be0 = (const float*)d_in[6];
  const float* w1 = (const float*)d_in[7];
  const float* b1 = (const float*)d_in[8];
  const float* g1 = (const float*)d_in[9];
  const float* be1 = (const float*)d_in[10];
  const float* w2 = (const float*)d_in[11];
  const float* b2 = (const float*)d_in[12];
  const float* g2 = (const float*)d_in[13];
  const float* be2 = (const float*)d_in[14];

  float* out = (float*)d_out;
  float* out_ct = out;
  float* out_cp = out + B_SZ * M_CENT;
  float* out_ft = out + 2 * B_SZ * M_CENT;

  char* ws = (char*)d_ws;
  uint32_t* bits1 = (uint32_t*)(ws + 0);           // 128 KB
  uint32_t* bits2 = (uint32_t*)(ws + 131072);      // 128 KB
  int* rank2 = (int*)(ws + 262144);                // 128 KB
  int* xmid  = (int*)(ws + 393216);                // 128 KB
  int* xfin  = (int*)(ws + 524288);                // xfin[0:1024] == cent_idx
  int* idx_buf = (int*)(ws + 655360);              // 4096*32*4 = 512 KB
  int* hist1   = (int*)(ws + 1179648);             // 256 KB
  int* hist2   = (int*)(ws + 1441792);             // 256 KB
  int* prefix1 = (int*)(ws + 1703936);             // 256 KB
  int* prefix2 = (int*)(ws + 1966080);             // 256 KB
  int* cursor1 = (int*)(ws + 2228224);             // 256 KB
  int* cursor2 = (int*)(ws + 2490368);             // 256 KB
  int* sorted1 = (int*)(ws + 2752512);             // 128 KB
  int* sorted2 = (int*)(ws + 2883584);             // 128 KB
  int* gbase1  = (int*)(ws + 3014656);             // 1 KB
  int* gbase2  = (int*)(ws + 3015680);             // 1 KB
  double* stats1 = (double*)(ws + 3016704);        // 64*2*32*8 = 32 KB
  double* stats2 = (double*)(ws + 3016704 + 32768);
  double* stats3 = (double*)(ws + 3016704 + 65536); // 64 KB
  float* weff1 = (float*)(ws + 3016704 + 131072);
  float* beff1 = weff1 + 32 * 16;
  float* weff2 = beff1 + 32;
  float* beff2 = weff2 + 32 * 32;
  float* weff3 = beff2 + 32;
  float* beff3 = weff3 + 64 * 32;

  hipMemsetAsync(hist1, 0, 524288, stream);        // hist1 + hist2
  hipMemsetAsync(stats1, 0, 131072, stream);       // stats1..3

  perm_bits_kernel<<<128, 256, 0, stream>>>(bits1, bits2);
  hist_kernel<<<128, 256, 0, stream>>>(bits1, bits2, hist1, hist2);
  gsum_scan_kernel<<<2, 256, 0, stream>>>(hist1, hist2, gbase1, gbase2);
  bucket_scan_kernel<<<dim3(256, 2), 256, 0, stream>>>(hist1, hist2, gbase1, gbase2,
                                                       prefix1, prefix2, cursor1, cursor2);
  bucket_scatter_kernel<<<128, 256, 0, stream>>>(bits1, bits2, cursor1, cursor2,
                                                 sorted1, sorted2);
  rank_scatter1_kernel<<<128, 256, 0, stream>>>(bits1, bits2, prefix1, prefix2,
                                                hist1, hist2, sorted1, sorted2,
                                                xmid, rank2);
  scatter2_kernel<<<128, 256, 0, stream>>>(rank2, xmid, xfin);

  select_kernel<<<B_SZ * M_CENT, 256, 0, stream>>>(theta, phi, xfin, idx_buf,
                                                   out_ct, out_cp);

  pass_stats1_kernel<<<B_SZ * M_CENT, 256, 0, stream>>>(feat, idx_buf, w0, b0, stats1);
  fixup_kernel<16, 32><<<1, 64, 0, stream>>>(stats1, w0, b0, g0, be0, weff1, beff1);
  pass_stats2_kernel<<<B_SZ * M_CENT, 256, 0, stream>>>(feat, idx_buf, weff1, beff1,
                                                        w1, b1, stats2);
  fixup_kernel<32, 32><<<1, 64, 0, stream>>>(stats2, w1, b1, g1, be1, weff2, beff2);
  pass_stats3_kernel<<<B_SZ * M_CENT, 256, 0, stream>>>(feat, idx_buf, weff1, beff1,
                                                        weff2, beff2, w2, b2, stats3);
  fixup_kernel<32, 64><<<1, 64, 0, stream>>>(stats3, w2, b2, g2, be2, weff3, beff3);
  pass_final_kernel<<<B_SZ * M_CENT, 256, 0, stream>>>(feat, idx_buf, weff1, beff1,
                                                       weff2, beff2, weff3, beff3, out_ft);
}

// Round 5
// 377.254 us; speedup vs baseline: 2.4946x; 1.2812x over previous
//
#include <hip/hip_runtime.h>
#include <stdint.h>

#define N_PTS 32768
#define M_CENT 1024
#define B_SZ 4
#define NS 32
#define NR 64
#define P_TOT (B_SZ * NS * M_CENT) /* 131072 */

// spatial grid: cell 0.11 > radius 0.1 => +/-1-cell window provably covers
#define GT 29
#define GP 58
#define NCELL (GT * GP) /* 1682 */
#define INVF (1.0f / 0.11f)
#define CAPW 320

__device__ __forceinline__ int cell_t(float t) {
  return min(GT - 1, (int)(t * INVF));
}
__device__ __forceinline__ int cell_p(float p) {
  return min(GP - 1, (int)(p * INVF));
}

// ---------------- threefry2x32 (JAX partitionable mode) ----------------
struct Key2 { uint32_t a, b; };

__device__ __forceinline__ uint32_t rotl32(uint32_t v, uint32_t r) {
  return (v << r) | (v >> (32u - r));
}

__device__ __forceinline__ void tf2x32(uint32_t k0, uint32_t k1,
                                       uint32_t& x0, uint32_t& x1) {
  uint32_t ks0 = k0, ks1 = k1, ks2 = k0 ^ k1 ^ 0x1BD11BDAu;
  x0 += ks0; x1 += ks1;
#define TF_ROUND(r) { x0 += x1; x1 = rotl32(x1, r); x1 ^= x0; }
  TF_ROUND(13u) TF_ROUND(15u) TF_ROUND(26u) TF_ROUND(6u)
  x0 += ks1; x1 += ks2 + 1u;
  TF_ROUND(17u) TF_ROUND(29u) TF_ROUND(16u) TF_ROUND(24u)
  x0 += ks2; x1 += ks0 + 2u;
  TF_ROUND(13u) TF_ROUND(15u) TF_ROUND(26u) TF_ROUND(6u)
  x0 += ks0; x1 += ks1 + 3u;
  TF_ROUND(17u) TF_ROUND(29u) TF_ROUND(16u) TF_ROUND(24u)
  x0 += ks1; x1 += ks2 + 4u;
  TF_ROUND(13u) TF_ROUND(15u) TF_ROUND(26u) TF_ROUND(6u)
  x0 += ks2; x1 += ks0 + 5u;
#undef TF_ROUND
}

__device__ __forceinline__ Key2 tf_block(Key2 k, uint32_t hi, uint32_t lo) {
  uint32_t x0 = hi, x1 = lo;
  tf2x32(k.a, k.b, x0, x1);
  Key2 r; r.a = x0; r.b = x1; return r;
}

// -------- permutation bits for the 2 shuffle rounds --------
__global__ __launch_bounds__(256) void perm_bits_kernel(uint32_t* __restrict__ bits1,
                                                        uint32_t* __restrict__ bits2) {
  int j = blockIdx.x * 256 + threadIdx.x;
  Key2 root; root.a = 0u; root.b = 42u;          // jax.random.key(42)
  Key2 k1   = tf_block(root, 0u, 0u);            // split(key)[0] -> permutation key
  Key2 keyA = tf_block(k1, 0u, 0u);
  Key2 sub1 = tf_block(k1, 0u, 1u);
  Key2 sub2 = tf_block(keyA, 0u, 1u);
  Key2 r1 = tf_block(sub1, 0u, (uint32_t)j);
  Key2 r2 = tf_block(sub2, 0u, (uint32_t)j);
  bits1[j] = r1.a ^ r1.b;
  bits2[j] = r2.a ^ r2.b;
}

// -------- counting-sort rank (O(N)) for the permutation --------
__global__ __launch_bounds__(256) void hist_kernel(const uint32_t* __restrict__ bits1,
                                                   const uint32_t* __restrict__ bits2,
                                                   int* __restrict__ hist1,
                                                   int* __restrict__ hist2) {
  int j = blockIdx.x * 256 + threadIdx.x;
  atomicAdd(&hist1[bits1[j] >> 16], 1);
  atomicAdd(&hist2[bits2[j] >> 16], 1);
}

__global__ __launch_bounds__(256) void gsum_scan_kernel(const int* __restrict__ hist1,
                                                        const int* __restrict__ hist2,
                                                        int* __restrict__ gbase1,
                                                        int* __restrict__ gbase2) {
  __shared__ int s[256];
  const int* hist = blockIdx.x == 0 ? hist1 : hist2;
  int* gbase = blockIdx.x == 0 ? gbase1 : gbase2;
  int g = threadIdx.x;
  int sum = 0;
  for (int i = 0; i < 256; ++i) sum += hist[g * 256 + i];
  s[g] = sum;
  __syncthreads();
  if (g == 0) {
    int run = 0;
    for (int i = 0; i < 256; ++i) { int t = s[i]; s[i] = run; run += t; }
  }
  __syncthreads();
  gbase[g] = s[g];
}

__global__ __launch_bounds__(256) void bucket_scan_kernel(const int* __restrict__ hist1,
                                                          const int* __restrict__ hist2,
                                                          const int* __restrict__ gbase1,
                                                          const int* __restrict__ gbase2,
                                                          int* __restrict__ prefix1,
                                                          int* __restrict__ prefix2,
                                                          int* __restrict__ cursor1,
                                                          int* __restrict__ cursor2) {
  __shared__ int s[256];
  const int* hist = blockIdx.y == 0 ? hist1 : hist2;
  const int* gbase = blockIdx.y == 0 ? gbase1 : gbase2;
  int* prefix = blockIdx.y == 0 ? prefix1 : prefix2;
  int* cursor = blockIdx.y == 0 ? cursor1 : cursor2;
  int g = blockIdx.x, t = threadIdx.x;
  int idx = g * 256 + t;
  int orig = hist[idx];
  s[t] = orig;
  __syncthreads();
  for (int off = 1; off < 256; off <<= 1) {
    int v = (t >= off) ? s[t - off] : 0;
    __syncthreads();
    s[t] += v;
    __syncthreads();
  }
  int pref = gbase[g] + s[t] - orig;
  prefix[idx] = pref;
  cursor[idx] = pref;
}

__global__ __launch_bounds__(256) void bucket_scatter_kernel(const uint32_t* __restrict__ bits1,
                                                             const uint32_t* __restrict__ bits2,
                                                             int* __restrict__ cursor1,
                                                             int* __restrict__ cursor2,
                                                             int* __restrict__ sorted1,
                                                             int* __restrict__ sorted2) {
  int j = blockIdx.x * 256 + threadIdx.x;
  int p1 = atomicAdd(&cursor1[bits1[j] >> 16], 1);
  sorted1[p1] = j;
  int p2 = atomicAdd(&cursor2[bits2[j] >> 16], 1);
  sorted2[p2] = j;
}

__device__ __forceinline__ int exact_rank(const uint32_t* __restrict__ bits,
                                          const int* __restrict__ prefix,
                                          const int* __restrict__ hist,
                                          const int* __restrict__ sorted, int j) {
  uint32_t my = bits[j];
  int b = (int)(my >> 16);
  int start = prefix[b];
  int cnt = hist[b];
  int r = start;
  for (int i = 0; i < cnt; ++i) {
    int m = sorted[start + i];
    uint32_t vb = bits[m];
    if (vb < my || (vb == my && m < j)) ++r;
  }
  return r;
}

__global__ __launch_bounds__(256) void rank_scatter1_kernel(
    const uint32_t* __restrict__ bits1, const uint32_t* __restrict__ bits2,
    const int* __restrict__ prefix1, const int* __restrict__ prefix2,
    const int* __restrict__ hist1, const int* __restrict__ hist2,
    const int* __restrict__ sorted1, const int* __restrict__ sorted2,
    int* __restrict__ xmid, int* __restrict__ rank2) {
  int j = blockIdx.x * 256 + threadIdx.x;
  int r1 = exact_rank(bits1, prefix1, hist1, sorted1, j);
  xmid[r1] = j;
  rank2[j] = exact_rank(bits2, prefix2, hist2, sorted2, j);
}

__global__ __launch_bounds__(256) void scatter2_kernel(const int* __restrict__ rank2,
                                                       const int* __restrict__ xmid,
                                                       int* __restrict__ xfin) {
  int p = blockIdx.x * 256 + threadIdx.x;
  xfin[rank2[p]] = xmid[p];
}

// -------- spatial grid build --------
__global__ __launch_bounds__(256) void cell_hist_kernel(const float* __restrict__ theta,
                                                        const float* __restrict__ phi,
                                                        int* __restrict__ cellcnt) {
  int j = blockIdx.x * 256 + threadIdx.x;      // 0 .. 4*32768
  int b = j >> 15;
  atomicAdd(&cellcnt[b * NCELL + cell_t(theta[j]) * GP + cell_p(phi[j])], 1);
}

__global__ __launch_bounds__(256) void cell_scan_kernel(const int* __restrict__ cellcnt,
                                                        int* __restrict__ cellpre,
                                                        int* __restrict__ cellcur) {
  __shared__ int s[256];
  int b = blockIdx.x, t = threadIdx.x;
  const int* cnt = cellcnt + b * NCELL;
  int i0 = t * 7, i1 = min(i0 + 7, NCELL);
  int sum = 0;
  for (int i = i0; i < i1; ++i) sum += cnt[i];
  s[t] = sum;
  __syncthreads();
  for (int off = 1; off < 256; off <<= 1) {
    int v = (t >= off) ? s[t - off] : 0;
    __syncthreads();
    s[t] += v;
    __syncthreads();
  }
  int run = (t == 0) ? 0 : s[t - 1];
  for (int i = i0; i < i1; ++i) {
    cellpre[b * NCELL + i] = run;
    cellcur[b * NCELL + i] = run;
    run += cnt[i];
  }
}

__global__ __launch_bounds__(256) void cell_scatter_kernel(const float* __restrict__ theta,
                                                           const float* __restrict__ phi,
                                                           int* __restrict__ cellcur,
                                                           float* __restrict__ px,
                                                           float* __restrict__ py,
                                                           int* __restrict__ pid) {
  int j = blockIdx.x * 256 + threadIdx.x;
  int b = j >> 15, n = j & (N_PTS - 1);
  float t = theta[j], p = phi[j];
  int cell = b * NCELL + cell_t(t) * GP + cell_p(p);
  int pos = atomicAdd(&cellcur[cell], 1);
  px[(b << 15) + pos] = t;
  py[(b << 15) + pos] = p;
  pid[(b << 15) + pos] = n;
}

// -------- neighbor selection: one WAVE per center (4 waves/block) --------
__global__ __launch_bounds__(256) void select_kernel(
    const float* __restrict__ theta, const float* __restrict__ phi,
    const int* __restrict__ cent,
    const int* __restrict__ cellpre, const int* __restrict__ cellcnt,
    const float* __restrict__ px, const float* __restrict__ py,
    const int* __restrict__ pid,
    int* __restrict__ idx_buf, float* __restrict__ out_ct, float* __restrict__ out_cp) {
  __shared__ float wsc[4][CAPW];
  __shared__ int wsn[4][CAPW];
  int tid = threadIdx.x;
  int w = tid >> 6, lane = tid & 63;
  int bm = blockIdx.x * 4 + w;
  int b = bm >> 10, m = bm & 1023;
  int ci = cent[m];
  float ctv = theta[(b << 15) + ci];
  float cpv = phi[(b << 15) + ci];
  if (lane == 0) { out_ct[bm] = ctv; out_cp[bm] = cpv; }

  Key2 root; root.a = 0u; root.b = 42u;
  Key2 k2 = tf_block(root, 0u, 1u);              // split(key)[1] -> scores key
  uint32_t flat_base = (uint32_t)bm << 15;

  int tc = cell_t(ctv), pc = cell_p(cpv);
  int t0 = max(0, tc - 1), t1 = min(GT - 1, tc + 1);
  int p0 = max(0, pc - 1), p1 = min(GP - 1, pc + 1);

  const float* bpx = px + ((size_t)b << 15);
  const float* bpy = py + ((size_t)b << 15);
  const int* bpid = pid + ((size_t)b << 15);
  int wcnt = 0;
  for (int tcell = t0; tcell <= t1; ++tcell) {
    for (int pcell = p0; pcell <= p1; ++pcell) {
      int cell = b * NCELL + tcell * GP + pcell;
      int start = cellpre[cell];
      int cnt = cellcnt[cell];
      for (int base = 0; base < cnt; base += 64) {
        int i = base + lane;
        bool hit = false; float sc = 0.0f; int n = 0;
        if (i < cnt) {
          float t = bpx[start + i], p = bpy[start + i];
          // match XLA's uncontracted f32 elementwise chain exactly
          float dx = __fsub_rn(t, ctv);
          float dy = __fsub_rn(p, cpv);
          float d = __fsqrt_rn(__fadd_rn(__fmul_rn(dx, dx), __fmul_rn(dy, dy)));
          if (d <= 0.1f) {
            hit = true; n = bpid[start + i];
            Key2 r = tf_block(k2, 0u, flat_base + (uint32_t)n);
            uint32_t bits = r.a ^ r.b;
            sc = __uint_as_float(0x3f800000u | (bits >> 9)) - 1.0f; // uniform [0,1)
          }
        }
        unsigned long long mask = __ballot(hit);
        int pos = wcnt + __popcll(mask & ((1ull << lane) - 1ull));
        if (hit && pos < CAPW) { wsc[w][pos] = sc; wsn[w][pos] = n; }
        wcnt = min(wcnt + (int)__popcll(mask), CAPW);
      }
    }
  }
  __syncthreads();

  // 32 rounds of lex-min (score, n) strictly greater than last selected
  // == stable top_k(-scores) incl. tie-breaks; pad with sel[0] (argmin)
  float ls = -1.0f; int ln = -1;
  int sel0 = -1, mysel = -1;
  for (int r = 0; r < NS; ++r) {
    float best = 3.0e38f; int bn = 0x7fffffff;
    for (int i = lane; i < wcnt; i += 64) {
      float s = wsc[w][i]; int n = wsn[w][i];
      bool after = (s > ls) || (s == ls && n > ln);
      bool better = (s < best) || (s == best && n < bn);
      if (after && better) { best = s; bn = n; }
    }
    for (int off = 32; off; off >>= 1) {
      float os = __shfl_xor(best, off);
      int on = __shfl_xor(bn, off);
      if (os < best || (os == best && on < bn)) { best = os; bn = on; }
    }
    int chosen;
    if (best < 3.0e38f) { ls = best; ln = bn; chosen = bn; }
    else chosen = sel0;
    if (r == 0) sel0 = chosen;
    if (lane == r) mysel = chosen;
  }
  if (lane < NS) idx_buf[bm * NS + lane] = mysel;
}

// -------- MLP --------
template <int CO>
__device__ __forceinline__ void accum_stats(const float* __restrict__ Y,
                                            double* __restrict__ S, int tid, int bid) {
  if (tid < CO) {
    double s1 = 0.0, s2 = 0.0;
#pragma unroll
    for (int s = 0; s < NS; ++s) {
      double v = (double)Y[tid * NS + s];
      s1 += v; s2 += v * v;
    }
    double* base = S + (size_t)(bid & (NR - 1)) * (2 * CO);
    atomicAdd(base + tid, s1);
    atomicAdd(base + CO + tid, s2);
  }
}

__device__ __forceinline__ float bn_relu(float y, float mu, float r, float g, float be) {
  float t = __fsub_rn(y, mu);
  t = __fmul_rn(t, r);
  t = __fmul_rn(t, g);
  t = __fadd_rn(t, be);
  return fmaxf(t, 0.0f);
}

__device__ __forceinline__ void load_x1(int big, const float* __restrict__ X1g,
                                        const float* __restrict__ feat,
                                        const int* __restrict__ idx_buf,
                                        int bm, int b, int tid,
                                        int* idxs, float* X1) {
  if (!big) {
    if (tid < NS) idxs[tid] = idx_buf[bm * NS + tid];
  }
  __syncthreads();
  if (big) {
    for (int v = tid; v < 512; v += 256) X1[v] = X1g[(size_t)bm * 512 + v];
  } else {
    for (int v = tid; v < 512; v += 256) {
      int c = v >> 5, s = v & 31;
      X1[v] = feat[(size_t)(b * 16 + c) * N_PTS + idxs[s]];
    }
  }
}

__global__ __launch_bounds__(256) void pass1_kernel(
    const float* __restrict__ feat, const int* __restrict__ idx_buf,
    const float* __restrict__ w0, const float* __restrict__ b0,
    float* __restrict__ X1g, double* __restrict__ stats, int big) {
  __shared__ int idxs[NS];
  __shared__ float X1[16 * NS];
  __shared__ float Y[32 * NS];
  int bm = blockIdx.x, tid = threadIdx.x, b = bm >> 10;
  if (tid < NS) idxs[tid] = idx_buf[bm * NS + tid];
  __syncthreads();
  for (int v = tid; v < 512; v += 256) {
    int c = v >> 5, s = v & 31;
    float val = feat[(size_t)(b * 16 + c) * N_PTS + idxs[s]];
    X1[v] = val;
    if (big) X1g[(size_t)bm * 512 + v] = val;
  }
  __syncthreads();
  for (int v = tid; v < 1024; v += 256) {
    int o = v >> 5, s = v & 31;
    float acc = b0[o];
#pragma unroll
    for (int c = 0; c < 16; ++c) acc = fmaf(w0[o * 16 + c], X1[c * 32 + s], acc);
    Y[v] = acc;
  }
  __syncthreads();
  accum_stats<32>(Y, stats, tid, bm);
}

__global__ __launch_bounds__(256) void pass2_kernel(
    const float* __restrict__ X1g, const float* __restrict__ feat,
    const int* __restrict__ idx_buf,
    const float* __restrict__ w0, const float* __restrict__ b0,
    const float* __restrict__ mur1, const float* __restrict__ g0, const float* __restrict__ be0,
    const float* __restrict__ w1, const float* __restrict__ b1,
    double* __restrict__ stats, int big) {
  __shared__ int idxs[NS];
  __shared__ float X1[512];
  __shared__ float X2[1024];
  __shared__ float Y[1024];
  int bm = blockIdx.x, tid = threadIdx.x, b = bm >> 10;
  load_x1(big, X1g, feat, idx_buf, bm, b, tid, idxs, X1);
  __syncthreads();
  for (int v = tid; v < 1024; v += 256) {
    int o = v >> 5, s = v & 31;
    float acc = b0[o];
#pragma unroll
    for (int c = 0; c < 16; ++c) acc = fmaf(w0[o * 16 + c], X1[c * 32 + s], acc);
    X2[v] = bn_relu(acc, mur1[o], mur1[32 + o], g0[o], be0[o]);
  }
  __syncthreads();
  for (int v = tid; v < 1024; v += 256) {
    int o = v >> 5, s = v & 31;
    float acc = b1[o];
#pragma unroll
    for (int c = 0; c < 32; ++c) acc = fmaf(w1[o * 32 + c], X2[c * 32 + s], acc);
    Y[v] = acc;
  }
  __syncthreads();
  accum_stats<32>(Y, stats, tid, bm);
}

__global__ __launch_bounds__(256) void pass3_kernel(
    const float* __restrict__ X1g, const float* __restrict__ feat,
    const int* __restrict__ idx_buf,
    const float* __restrict__ w0, const float* __restrict__ b0,
    const float* __restrict__ mur1, const float* __restrict__ g0, const float* __restrict__ be0,
    const float* __restrict__ w1, const float* __restrict__ b1,
    const float* __restrict__ mur2, const float* __restrict__ g1, const float* __restrict__ be1,
    const float* __restrict__ w2, const float* __restrict__ b2,
    double* __restrict__ stats, int big) {
  __shared__ int idxs[NS];
  __shared__ float X1[512];
  __shared__ float X2[1024];
  __shared__ float X3[1024];
  __shared__ float Y[2048];
  int bm = blockIdx.x, tid = threadIdx.x, b = bm >> 10;
  load_x1(big, X1g, feat, idx_buf, bm, b, tid, idxs, X1);
  __syncthreads();
  for (int v = tid; v < 1024; v += 256) {
    int o = v >> 5, s = v & 31;
    float acc = b0[o];
#pragma unroll
    for (int c = 0; c < 16; ++c) acc = fmaf(w0[o * 16 + c], X1[c * 32 + s], acc);
    X2[v] = bn_relu(acc, mur1[o], mur1[32 + o], g0[o], be0[o]);
  }
  __syncthreads();
  for (int v = tid; v < 1024; v += 256) {
    int o = v >> 5, s = v & 31;
    float acc = b1[o];
#pragma unroll
    for (int c = 0; c < 32; ++c) acc = fmaf(w1[o * 32 + c], X2[c * 32 + s], acc);
    X3[v] = bn_relu(acc, mur2[o], mur2[32 + o], g1[o], be1[o]);
  }
  __syncthreads();
  for (int v = tid; v < 2048; v += 256) {
    int o = v >> 5, s = v & 31;
    float acc = b2[o];
#pragma unroll
    for (int c = 0; c < 32; ++c) acc = fmaf(w2[o * 32 + c], X3[c * 32 + s], acc);
    Y[v] = acc;
  }
  __syncthreads();
  accum_stats<64>(Y, stats, tid, bm);
}

__global__ __launch_bounds__(256) void final_kernel(
    const float* __restrict__ X1g, const float* __restrict__ feat,
    const int* __restrict__ idx_buf,
    const float* __restrict__ w0, const float* __restrict__ b0,
    const float* __restrict__ mur1, const float* __restrict__ g0, const float* __restrict__ be0,
    const float* __restrict__ w1, const float* __restrict__ b1,
    const float* __restrict__ mur2, const float* __restrict__ g1, const float* __restrict__ be1,
    const float* __restrict__ w2, const float* __restrict__ b2,
    const float* __restrict__ mur3, const float* __restrict__ g2, const float* __restrict__ be2,
    float* __restrict__ out_ft, int big) {
  __shared__ int idxs[NS];
  __shared__ float X1[512];
  __shared__ float X2[1024];
  __shared__ float X3[1024];
  __shared__ float Y[2048];
  int bm = blockIdx.x, tid = threadIdx.x, b = bm >> 10, m = bm & 1023;
  load_x1(big, X1g, feat, idx_buf, bm, b, tid, idxs, X1);
  __syncthreads();
  for (int v = tid; v < 1024; v += 256) {
    int o = v >> 5, s = v & 31;
    float acc = b0[o];
#pragma unroll
    for (int c = 0; c < 16; ++c) acc = fmaf(w0[o * 16 + c], X1[c * 32 + s], acc);
    X2[v] = bn_relu(acc, mur1[o], mur1[32 + o], g0[o], be0[o]);
  }
  __syncthreads();
  for (int v = tid; v < 1024; v += 256) {
    int o = v >> 5, s = v & 31;
    float acc = b1[o];
#pragma unroll
    for (int c = 0; c < 32; ++c) acc = fmaf(w1[o * 32 + c], X2[c * 32 + s], acc);
    X3[v] = bn_relu(acc, mur2[o], mur2[32 + o], g1[o], be1[o]);
  }
  __syncthreads();
  for (int v = tid; v < 2048; v += 256) {
    int o = v >> 5, s = v & 31;
    float acc = b2[o];
#pragma unroll
    for (int c = 0; c < 32; ++c) acc = fmaf(w2[o * 32 + c], X3[c * 32 + s], acc);
    Y[v] = acc;
  }
  __syncthreads();
  if (tid < 64) {
    float mx = -3.0e38f;
#pragma unroll
    for (int s = 0; s < NS; ++s)
      mx = fmaxf(mx, bn_relu(Y[tid * 32 + s], mur3[tid], mur3[64 + tid], g2[tid], be2[tid]));
    out_ft[(size_t)(b * 64 + tid) * M_CENT + m] = mx;
  }
}

template <int CO>
__global__ void fixup_mur_kernel(const double* __restrict__ S, float* __restrict__ mur) {
  int o = threadIdx.x;
  if (o >= CO) return;
  double s1 = 0.0, s2 = 0.0;
  for (int r = 0; r < NR; ++r) {
    s1 += S[r * 2 * CO + o];
    s2 += S[r * 2 * CO + CO + o];
  }
  const double P = (double)P_TOT;
  double mu = s1 / P;
  double var = s2 / P - mu * mu;
  mur[o] = (float)mu;
  mur[CO + o] = (float)(1.0 / sqrt(var + 1e-5));
}

extern "C" void kernel_launch(void* const* d_in, const int* in_sizes, int n_in,
                              void* d_out, int out_size, void* d_ws, size_t ws_size,
                              hipStream_t stream) {
  (void)in_sizes; (void)n_in; (void)out_size;
  const float* theta = (const float*)d_in[0];
  const float* phi   = (const float*)d_in[1];
  const float* feat  = (const float*)d_in[2];
  const float* w0 = (const float*)d_in[3];
  const float* b0 = (const float*)d_in[4];
  const float* g0 = (const float*)d_in[5];
  const float* be0 = (const float*)d_in[6];
  const float* w1 = (const float*)d_in[7];
  const float* b1 = (const float*)d_in[8];
  const float* g1 = (const float*)d_in[9];
  const float* be1 = (const float*)d_in[10];
  const float* w2 = (const float*)d_in[11];
  const float* b2 = (const float*)d_in[12];
  const float* g2 = (const float*)d_in[13];
  const float* be2 = (const float*)d_in[14];

  float* out = (float*)d_out;
  float* out_ct = out;
  float* out_cp = out + B_SZ * M_CENT;
  float* out_ft = out + 2 * B_SZ * M_CENT;

  char* ws = (char*)d_ws;
  uint32_t* bits1 = (uint32_t*)(ws + 0);
  uint32_t* bits2 = (uint32_t*)(ws + 131072);
  int* rank2 = (int*)(ws + 262144);
  int* xmid  = (int*)(ws + 393216);
  int* xfin  = (int*)(ws + 524288);      // xfin[0:1024] == cent_idx
  int* idx_buf = (int*)(ws + 655360);    // [4096][32]
  int* hist1   = (int*)(ws + 1179648);
  int* hist2   = (int*)(ws + 1441792);
  int* prefix1 = (int*)(ws + 1703936);
  int* prefix2 = (int*)(ws + 1966080);
  int* cursor1 = (int*)(ws + 2228224);
  int* cursor2 = (int*)(ws + 2490368);
  int* sorted1 = (int*)(ws + 2752512);
  int* sorted2 = (int*)(ws + 2883584);
  int* gbase1  = (int*)(ws + 3014656);
  int* gbase2  = (int*)(ws + 3015680);
  int* cellcnt = (int*)(ws + 3016704);   // 4*1682*4 < 32768
  int* cellpre = (int*)(ws + 3049472);
  int* cellcur = (int*)(ws + 3082240);
  float* px    = (float*)(ws + 3115008); // 512 KB
  float* py    = (float*)(ws + 3639296);
  int* pid     = (int*)(ws + 4163584);
  double* stats1 = (double*)(ws + 4687872);   // 32 KB
  double* stats2 = (double*)(ws + 4720640);   // 32 KB
  double* stats3 = (double*)(ws + 4753408);   // 64 KB
  float* mur1 = (float*)(ws + 4818944);
  float* mur2 = (float*)(ws + 4819200);
  float* mur3 = (float*)(ws + 4819456);
  float* X1g  = (float*)(ws + 4819968);       // 8 MB
  int big = (ws_size >= (size_t)4819968 + 8388608) ? 1 : 0;

  hipMemsetAsync(hist1, 0, 524288, stream);        // hist1 + hist2
  hipMemsetAsync(cellcnt, 0, 32768, stream);
  hipMemsetAsync(stats1, 0, 131072, stream);       // stats1..3

  perm_bits_kernel<<<128, 256, 0, stream>>>(bits1, bits2);
  hist_kernel<<<128, 256, 0, stream>>>(bits1, bits2, hist1, hist2);
  gsum_scan_kernel<<<2, 256, 0, stream>>>(hist1, hist2, gbase1, gbase2);
  bucket_scan_kernel<<<dim3(256, 2), 256, 0, stream>>>(hist1, hist2, gbase1, gbase2,
                                                       prefix1, prefix2, cursor1, cursor2);
  bucket_scatter_kernel<<<128, 256, 0, stream>>>(bits1, bits2, cursor1, cursor2,
                                                 sorted1, sorted2);
  rank_scatter1_kernel<<<128, 256, 0, stream>>>(bits1, bits2, prefix1, prefix2,
                                                hist1, hist2, sorted1, sorted2,
                                                xmid, rank2);
  scatter2_kernel<<<128, 256, 0, stream>>>(rank2, xmid, xfin);

  cell_hist_kernel<<<512, 256, 0, stream>>>(theta, phi, cellcnt);
  cell_scan_kernel<<<4, 256, 0, stream>>>(cellcnt, cellpre, cellcur);
  cell_scatter_kernel<<<512, 256, 0, stream>>>(theta, phi, cellcur, px, py, pid);

  select_kernel<<<1024, 256, 0, stream>>>(theta, phi, xfin, cellpre, cellcnt,
                                          px, py, pid, idx_buf, out_ct, out_cp);

  pass1_kernel<<<4096, 256, 0, stream>>>(feat, idx_buf, w0, b0, X1g, stats1, big);
  fixup_mur_kernel<32><<<1, 64, 0, stream>>>(stats1, mur1);
  pass2_kernel<<<4096, 256, 0, stream>>>(X1g, feat, idx_buf, w0, b0, mur1, g0, be0,
                                         w1, b1, stats2, big);
  fixup_mur_kernel<32><<<1, 64, 0, stream>>>(stats2, mur2);
  pass3_kernel<<<4096, 256, 0, stream>>>(X1g, feat, idx_buf, w0, b0, mur1, g0, be0,
                                         w1, b1, mur2, g1, be1, w2, b2, stats3, big);
  fixup_mur_kernel<64><<<1, 64, 0, stream>>>(stats3, mur3);
  final_kernel<<<4096, 256, 0, stream>>>(X1g, feat, idx_buf, w0, b0, mur1, g0, be0,
                                         w1, b1, mur2, g1, be1, w2, b2, mur3, g2, be2,
                                         out_ft, big);
}

// Round 6
// 288.998 us; speedup vs baseline: 3.2564x; 1.3054x over previous
//
#include <hip/hip_runtime.h>
#include <stdint.h>

#define N_PTS 32768
#define M_CENT 1024
#define B_SZ 4
#define NS 32
#define NR 64
#define P_TOT (B_SZ * NS * M_CENT) /* 131072 */

// spatial grid: cell 0.11 > radius 0.1 => +/-1-cell window provably covers
#define GT 29
#define GP 58
#define NCELL (GT * GP) /* 1682 */
#define INVF (1.0f / 0.11f)
#define CAPW 320

__device__ __forceinline__ int cell_t(float t) {
  return min(GT - 1, (int)(t * INVF));
}
__device__ __forceinline__ int cell_p(float p) {
  return min(GP - 1, (int)(p * INVF));
}

// ---------------- threefry2x32 (JAX partitionable mode) ----------------
struct Key2 { uint32_t a, b; };

__device__ __forceinline__ uint32_t rotl32(uint32_t v, uint32_t r) {
  return (v << r) | (v >> (32u - r));
}

__device__ __forceinline__ void tf2x32(uint32_t k0, uint32_t k1,
                                       uint32_t& x0, uint32_t& x1) {
  uint32_t ks0 = k0, ks1 = k1, ks2 = k0 ^ k1 ^ 0x1BD11BDAu;
  x0 += ks0; x1 += ks1;
#define TF_ROUND(r) { x0 += x1; x1 = rotl32(x1, r); x1 ^= x0; }
  TF_ROUND(13u) TF_ROUND(15u) TF_ROUND(26u) TF_ROUND(6u)
  x0 += ks1; x1 += ks2 + 1u;
  TF_ROUND(17u) TF_ROUND(29u) TF_ROUND(16u) TF_ROUND(24u)
  x0 += ks2; x1 += ks0 + 2u;
  TF_ROUND(13u) TF_ROUND(15u) TF_ROUND(26u) TF_ROUND(6u)
  x0 += ks0; x1 += ks1 + 3u;
  TF_ROUND(17u) TF_ROUND(29u) TF_ROUND(16u) TF_ROUND(24u)
  x0 += ks1; x1 += ks2 + 4u;
  TF_ROUND(13u) TF_ROUND(15u) TF_ROUND(26u) TF_ROUND(6u)
  x0 += ks2; x1 += ks0 + 5u;
#undef TF_ROUND
}

__device__ __forceinline__ Key2 tf_block(Key2 k, uint32_t hi, uint32_t lo) {
  uint32_t x0 = hi, x1 = lo;
  tf2x32(k.a, k.b, x0, x1);
  Key2 r; r.a = x0; r.b = x1; return r;
}

// -------- permutation bits for the 2 shuffle rounds --------
__global__ __launch_bounds__(256) void perm_bits_kernel(uint32_t* __restrict__ bits1,
                                                        uint32_t* __restrict__ bits2) {
  int j = blockIdx.x * 256 + threadIdx.x;
  Key2 root; root.a = 0u; root.b = 42u;          // jax.random.key(42)
  Key2 k1   = tf_block(root, 0u, 0u);            // split(key)[0] -> permutation key
  Key2 keyA = tf_block(k1, 0u, 0u);
  Key2 sub1 = tf_block(k1, 0u, 1u);
  Key2 sub2 = tf_block(keyA, 0u, 1u);
  Key2 r1 = tf_block(sub1, 0u, (uint32_t)j);
  Key2 r2 = tf_block(sub2, 0u, (uint32_t)j);
  bits1[j] = r1.a ^ r1.b;
  bits2[j] = r2.a ^ r2.b;
}

// -------- counting-sort rank (O(N)) for the permutation --------
__global__ __launch_bounds__(256) void hist_kernel(const uint32_t* __restrict__ bits1,
                                                   const uint32_t* __restrict__ bits2,
                                                   int* __restrict__ hist1,
                                                   int* __restrict__ hist2) {
  int j = blockIdx.x * 256 + threadIdx.x;
  atomicAdd(&hist1[bits1[j] >> 16], 1);
  atomicAdd(&hist2[bits2[j] >> 16], 1);
}

__global__ __launch_bounds__(256) void gsum_scan_kernel(const int* __restrict__ hist1,
                                                        const int* __restrict__ hist2,
                                                        int* __restrict__ gbase1,
                                                        int* __restrict__ gbase2) {
  __shared__ int s[256];
  const int* hist = blockIdx.x == 0 ? hist1 : hist2;
  int* gbase = blockIdx.x == 0 ? gbase1 : gbase2;
  int g = threadIdx.x;
  int sum = 0;
  for (int i = 0; i < 256; ++i) sum += hist[g * 256 + i];
  s[g] = sum;
  __syncthreads();
  if (g == 0) {
    int run = 0;
    for (int i = 0; i < 256; ++i) { int t = s[i]; s[i] = run; run += t; }
  }
  __syncthreads();
  gbase[g] = s[g];
}

__global__ __launch_bounds__(256) void bucket_scan_kernel(const int* __restrict__ hist1,
                                                          const int* __restrict__ hist2,
                                                          const int* __restrict__ gbase1,
                                                          const int* __restrict__ gbase2,
                                                          int* __restrict__ prefix1,
                                                          int* __restrict__ prefix2,
                                                          int* __restrict__ cursor1,
                                                          int* __restrict__ cursor2) {
  __shared__ int s[256];
  const int* hist = blockIdx.y == 0 ? hist1 : hist2;
  const int* gbase = blockIdx.y == 0 ? gbase1 : gbase2;
  int* prefix = blockIdx.y == 0 ? prefix1 : prefix2;
  int* cursor = blockIdx.y == 0 ? cursor1 : cursor2;
  int g = blockIdx.x, t = threadIdx.x;
  int idx = g * 256 + t;
  int orig = hist[idx];
  s[t] = orig;
  __syncthreads();
  for (int off = 1; off < 256; off <<= 1) {
    int v = (t >= off) ? s[t - off] : 0;
    __syncthreads();
    s[t] += v;
    __syncthreads();
  }
  int pref = gbase[g] + s[t] - orig;
  prefix[idx] = pref;
  cursor[idx] = pref;
}

__global__ __launch_bounds__(256) void bucket_scatter_kernel(const uint32_t* __restrict__ bits1,
                                                             const uint32_t* __restrict__ bits2,
                                                             int* __restrict__ cursor1,
                                                             int* __restrict__ cursor2,
                                                             int* __restrict__ sorted1,
                                                             int* __restrict__ sorted2) {
  int j = blockIdx.x * 256 + threadIdx.x;
  int p1 = atomicAdd(&cursor1[bits1[j] >> 16], 1);
  sorted1[p1] = j;
  int p2 = atomicAdd(&cursor2[bits2[j] >> 16], 1);
  sorted2[p2] = j;
}

__device__ __forceinline__ int exact_rank(const uint32_t* __restrict__ bits,
                                          const int* __restrict__ prefix,
                                          const int* __restrict__ hist,
                                          const int* __restrict__ sorted, int j) {
  uint32_t my = bits[j];
  int b = (int)(my >> 16);
  int start = prefix[b];
  int cnt = hist[b];
  int r = start;
  for (int i = 0; i < cnt; ++i) {
    int m = sorted[start + i];
    uint32_t vb = bits[m];
    if (vb < my || (vb == my && m < j)) ++r;
  }
  return r;
}

__global__ __launch_bounds__(256) void rank_scatter1_kernel(
    const uint32_t* __restrict__ bits1, const uint32_t* __restrict__ bits2,
    const int* __restrict__ prefix1, const int* __restrict__ prefix2,
    const int* __restrict__ hist1, const int* __restrict__ hist2,
    const int* __restrict__ sorted1, const int* __restrict__ sorted2,
    int* __restrict__ xmid, int* __restrict__ rank2) {
  int j = blockIdx.x * 256 + threadIdx.x;
  int r1 = exact_rank(bits1, prefix1, hist1, sorted1, j);
  xmid[r1] = j;
  rank2[j] = exact_rank(bits2, prefix2, hist2, sorted2, j);
}

__global__ __launch_bounds__(256) void scatter2_kernel(const int* __restrict__ rank2,
                                                       const int* __restrict__ xmid,
                                                       int* __restrict__ xfin) {
  int p = blockIdx.x * 256 + threadIdx.x;
  xfin[rank2[p]] = xmid[p];
}

// -------- spatial grid build --------
__global__ __launch_bounds__(256) void cell_hist_kernel(const float* __restrict__ theta,
                                                        const float* __restrict__ phi,
                                                        int* __restrict__ cellcnt) {
  int j = blockIdx.x * 256 + threadIdx.x;
  int b = j >> 15;
  atomicAdd(&cellcnt[b * NCELL + cell_t(theta[j]) * GP + cell_p(phi[j])], 1);
}

__global__ __launch_bounds__(256) void cell_scan_kernel(const int* __restrict__ cellcnt,
                                                        int* __restrict__ cellpre,
                                                        int* __restrict__ cellcur) {
  __shared__ int s[256];
  int b = blockIdx.x, t = threadIdx.x;
  const int* cnt = cellcnt + b * NCELL;
  int i0 = t * 7, i1 = min(i0 + 7, NCELL);
  int sum = 0;
  for (int i = i0; i < i1; ++i) sum += cnt[i];
  s[t] = sum;
  __syncthreads();
  for (int off = 1; off < 256; off <<= 1) {
    int v = (t >= off) ? s[t - off] : 0;
    __syncthreads();
    s[t] += v;
    __syncthreads();
  }
  int run = (t == 0) ? 0 : s[t - 1];
  for (int i = i0; i < i1; ++i) {
    cellpre[b * NCELL + i] = run;
    cellcur[b * NCELL + i] = run;
    run += cnt[i];
  }
}

__global__ __launch_bounds__(256) void cell_scatter_kernel(const float* __restrict__ theta,
                                                           const float* __restrict__ phi,
                                                           int* __restrict__ cellcur,
                                                           float* __restrict__ px,
                                                           float* __restrict__ py,
                                                           int* __restrict__ pid) {
  int j = blockIdx.x * 256 + threadIdx.x;
  int b = j >> 15, n = j & (N_PTS - 1);
  float t = theta[j], p = phi[j];
  int cell = b * NCELL + cell_t(t) * GP + cell_p(p);
  int pos = atomicAdd(&cellcur[cell], 1);
  px[(b << 15) + pos] = t;
  py[(b << 15) + pos] = p;
  pid[(b << 15) + pos] = n;
}

// -------- neighbor selection: one WAVE per center (4 waves/block) --------
__global__ __launch_bounds__(256) void select_kernel(
    const float* __restrict__ theta, const float* __restrict__ phi,
    const int* __restrict__ cent,
    const int* __restrict__ cellpre, const int* __restrict__ cellcnt,
    const float* __restrict__ px, const float* __restrict__ py,
    const int* __restrict__ pid,
    int* __restrict__ idx_buf, float* __restrict__ out_ct, float* __restrict__ out_cp) {
  __shared__ float wsc[4][CAPW];
  __shared__ int wsn[4][CAPW];
  int tid = threadIdx.x;
  int w = tid >> 6, lane = tid & 63;
  int bm = blockIdx.x * 4 + w;
  int b = bm >> 10, m = bm & 1023;
  int ci = cent[m];
  float ctv = theta[(b << 15) + ci];
  float cpv = phi[(b << 15) + ci];
  if (lane == 0) { out_ct[bm] = ctv; out_cp[bm] = cpv; }

  Key2 root; root.a = 0u; root.b = 42u;
  Key2 k2 = tf_block(root, 0u, 1u);              // split(key)[1] -> scores key
  uint32_t flat_base = (uint32_t)bm << 15;

  int tc = cell_t(ctv), pc = cell_p(cpv);
  int t0 = max(0, tc - 1), t1 = min(GT - 1, tc + 1);
  int p0 = max(0, pc - 1), p1 = min(GP - 1, pc + 1);

  const float* bpx = px + ((size_t)b << 15);
  const float* bpy = py + ((size_t)b << 15);
  const int* bpid = pid + ((size_t)b << 15);
  int wcnt = 0;
  for (int tcell = t0; tcell <= t1; ++tcell) {
    for (int pcell = p0; pcell <= p1; ++pcell) {
      int cell = b * NCELL + tcell * GP + pcell;
      int start = cellpre[cell];
      int cnt = cellcnt[cell];
      for (int base = 0; base < cnt; base += 64) {
        int i = base + lane;
        bool hit = false; float sc = 0.0f; int n = 0;
        if (i < cnt) {
          float t = bpx[start + i], p = bpy[start + i];
          // match XLA's uncontracted f32 elementwise chain exactly
          float dx = __fsub_rn(t, ctv);
          float dy = __fsub_rn(p, cpv);
          float d = __fsqrt_rn(__fadd_rn(__fmul_rn(dx, dx), __fmul_rn(dy, dy)));
          if (d <= 0.1f) {
            hit = true; n = bpid[start + i];
            Key2 r = tf_block(k2, 0u, flat_base + (uint32_t)n);
            uint32_t bits = r.a ^ r.b;
            sc = __uint_as_float(0x3f800000u | (bits >> 9)) - 1.0f; // uniform [0,1)
          }
        }
        unsigned long long mask = __ballot(hit);
        int pos = wcnt + __popcll(mask & ((1ull << lane) - 1ull));
        if (hit && pos < CAPW) { wsc[w][pos] = sc; wsn[w][pos] = n; }
        wcnt = min(wcnt + (int)__popcll(mask), CAPW);
      }
    }
  }
  __syncthreads();

  // 32 rounds of lex-min (score, n) strictly greater than last selected
  float ls = -1.0f; int ln = -1;
  int sel0 = -1, mysel = -1;
  for (int r = 0; r < NS; ++r) {
    float best = 3.0e38f; int bn = 0x7fffffff;
    for (int i = lane; i < wcnt; i += 64) {
      float s = wsc[w][i]; int n = wsn[w][i];
      bool after = (s > ls) || (s == ls && n > ln);
      bool better = (s < best) || (s == best && n < bn);
      if (after && better) { best = s; bn = n; }
    }
    for (int off = 32; off; off >>= 1) {
      float os = __shfl_xor(best, off);
      int on = __shfl_xor(bn, off);
      if (os < best || (os == best && on < bn)) { best = os; bn = on; }
    }
    int chosen;
    if (best < 3.0e38f) { ls = best; ln = bn; chosen = bn; }
    else chosen = sel0;
    if (r == 0) sel0 = chosen;
    if (lane == r) mysel = chosen;
  }
  if (lane < NS) idx_buf[bm * NS + lane] = mysel;
}

// -------- MLP --------
__device__ __forceinline__ float bn_relu(float y, float mu, float r, float g, float be) {
  float t = __fsub_rn(y, mu);
  t = __fmul_rn(t, r);
  t = __fmul_rn(t, g);
  t = __fadd_rn(t, be);
  return fmaxf(t, 0.0f);
}

// stats from padded LDS Y[CO][33] -> conflict-free column reads
template <int CO>
__device__ __forceinline__ void accum_stats_pad(const float* __restrict__ Yp,
                                                double* __restrict__ S, int tid, int bid) {
  if (tid < CO) {
    double s1 = 0.0, s2 = 0.0;
#pragma unroll
    for (int s = 0; s < NS; ++s) {
      double v = (double)Yp[tid * 33 + s];
      s1 += v; s2 += v * v;
    }
    double* base = S + (size_t)(bid & (NR - 1)) * (2 * CO);
    atomicAdd(base + tid, s1);
    atomicAdd(base + CO + tid, s2);
  }
}

// pass1: gather + L1 -> Y1g (mode2) / X1g (mode1) ; stats1
__global__ __launch_bounds__(256) void pass1_kernel(
    const float* __restrict__ feat, const int* __restrict__ idx_buf,
    const float* __restrict__ w0, const float* __restrict__ b0,
    float* __restrict__ stash, double* __restrict__ stats, int mode) {
  __shared__ int idxs[NS];
  __shared__ float X1[512];
  __shared__ float Yp[32 * 33];
  int bm = blockIdx.x, tid = threadIdx.x, b = bm >> 10;
  if (tid < NS) idxs[tid] = idx_buf[bm * NS + tid];
  __syncthreads();
  for (int v = tid; v < 512; v += 256) {
    int c = v >> 5, s = v & 31;
    float val = feat[(size_t)(b * 16 + c) * N_PTS + idxs[s]];
    X1[v] = val;
    if (mode == 1) stash[(size_t)bm * 512 + v] = val;
  }
  __syncthreads();
  for (int v = tid; v < 1024; v += 256) {
    int o = v >> 5, s = v & 31;
    float acc = b0[o];
#pragma unroll
    for (int c = 0; c < 16; ++c) acc = fmaf(w0[o * 16 + c], X1[c * 32 + s], acc);
    Yp[o * 33 + s] = acc;
    if (mode == 2) stash[(size_t)bm * 1024 + v] = acc;
  }
  __syncthreads();
  accum_stats_pad<32>(Yp, stats, tid, bm);
}

// pass2 (stash): read Y1g, bn1+relu, L2 -> Y2g ; stats2
__global__ __launch_bounds__(256) void pass2s_kernel(
    const float* __restrict__ Y1g,
    const float* __restrict__ mur1, const float* __restrict__ g0, const float* __restrict__ be0,
    const float* __restrict__ w1, const float* __restrict__ b1,
    float* __restrict__ Y2g, double* __restrict__ stats) {
  __shared__ float X2[1024];
  __shared__ float Yp[32 * 33];
  int bm = blockIdx.x, tid = threadIdx.x;
  for (int v = tid; v < 1024; v += 256) {
    int o = v >> 5;
    X2[v] = bn_relu(Y1g[(size_t)bm * 1024 + v], mur1[o], mur1[32 + o], g0[o], be0[o]);
  }
  __syncthreads();
  for (int v = tid; v < 1024; v += 256) {
    int o = v >> 5, s = v & 31;
    float acc = b1[o];
#pragma unroll
    for (int c = 0; c < 32; ++c) acc = fmaf(w1[o * 32 + c], X2[c * 32 + s], acc);
    Yp[o * 33 + s] = acc;
    Y2g[(size_t)bm * 1024 + v] = acc;
  }
  __syncthreads();
  accum_stats_pad<32>(Yp, stats, tid, bm);
}

// pass3 (stash): read Y2g, bn2+relu, L3 ; stats3 + per-(bm,o) min/max of Y3
__global__ __launch_bounds__(256) void pass3s_kernel(
    const float* __restrict__ Y2g,
    const float* __restrict__ mur2, const float* __restrict__ g1, const float* __restrict__ be1,
    const float* __restrict__ w2, const float* __restrict__ b2,
    float* __restrict__ mm3, double* __restrict__ stats) {
  __shared__ float X3[1024];
  __shared__ float Yp[64 * 33];
  int bm = blockIdx.x, tid = threadIdx.x;
  for (int v = tid; v < 1024; v += 256) {
    int o = v >> 5;
    X3[v] = bn_relu(Y2g[(size_t)bm * 1024 + v], mur2[o], mur2[32 + o], g1[o], be1[o]);
  }
  __syncthreads();
  for (int v = tid; v < 2048; v += 256) {
    int o = v >> 5, s = v & 31;
    float acc = b2[o];
#pragma unroll
    for (int c = 0; c < 32; ++c) acc = fmaf(w2[o * 32 + c], X3[c * 32 + s], acc);
    Yp[o * 33 + s] = acc;
  }
  __syncthreads();
  if (tid < 64) {
    double s1 = 0.0, s2 = 0.0;
    float mx = -3.0e38f, mn = 3.0e38f;
#pragma unroll
    for (int s = 0; s < NS; ++s) {
      float y = Yp[tid * 33 + s];
      double v = (double)y;
      s1 += v; s2 += v * v;
      mx = fmaxf(mx, y); mn = fminf(mn, y);
    }
    double* base = stats + (size_t)(bm & (NR - 1)) * 128;
    atomicAdd(base + tid, s1);
    atomicAdd(base + 64 + tid, s2);
    mm3[bm * 128 + tid * 2] = mx;
    mm3[bm * 128 + tid * 2 + 1] = mn;
  }
}

// final (stash): BN3 applied to the extremum; exact because bn_relu is
// weakly monotone in y (nondecreasing if g>=0, nonincreasing if g<0)
__global__ __launch_bounds__(256) void final_small_kernel(
    const float* __restrict__ mm3,
    const float* __restrict__ mur3, const float* __restrict__ g2, const float* __restrict__ be2,
    float* __restrict__ out_ft) {
  int j = blockIdx.x * 256 + threadIdx.x;          // (b*64+o)*1024+m
  int b = j >> 16, o = (j >> 10) & 63, m = j & 1023;
  int bm = b * 1024 + m;
  float g = g2[o];
  float y = (g >= 0.0f) ? mm3[bm * 128 + o * 2] : mm3[bm * 128 + o * 2 + 1];
  out_ft[j] = bn_relu(y, mur3[o], mur3[64 + o], g, be2[o]);
}

// -------- fallback recompute kernels (used when ws too small) --------
__device__ __forceinline__ void load_x1(int big, const float* __restrict__ X1g,
                                        const float* __restrict__ feat,
                                        const int* __restrict__ idx_buf,
                                        int bm, int b, int tid,
                                        int* idxs, float* X1) {
  if (!big) {
    if (tid < NS) idxs[tid] = idx_buf[bm * NS + tid];
  }
  __syncthreads();
  if (big) {
    for (int v = tid; v < 512; v += 256) X1[v] = X1g[(size_t)bm * 512 + v];
  } else {
    for (int v = tid; v < 512; v += 256) {
      int c = v >> 5, s = v & 31;
      X1[v] = feat[(size_t)(b * 16 + c) * N_PTS + idxs[s]];
    }
  }
}

__global__ __launch_bounds__(256) void pass2_rec_kernel(
    const float* __restrict__ X1g, const float* __restrict__ feat,
    const int* __restrict__ idx_buf,
    const float* __restrict__ w0, const float* __restrict__ b0,
    const float* __restrict__ mur1, const float* __restrict__ g0, const float* __restrict__ be0,
    const float* __restrict__ w1, const float* __restrict__ b1,
    double* __restrict__ stats, int big) {
  __shared__ int idxs[NS];
  __shared__ float X1[512];
  __shared__ float X2[1024];
  __shared__ float Yp[32 * 33];
  int bm = blockIdx.x, tid = threadIdx.x, b = bm >> 10;
  load_x1(big, X1g, feat, idx_buf, bm, b, tid, idxs, X1);
  __syncthreads();
  for (int v = tid; v < 1024; v += 256) {
    int o = v >> 5, s = v & 31;
    float acc = b0[o];
#pragma unroll
    for (int c = 0; c < 16; ++c) acc = fmaf(w0[o * 16 + c], X1[c * 32 + s], acc);
    X2[v] = bn_relu(acc, mur1[o], mur1[32 + o], g0[o], be0[o]);
  }
  __syncthreads();
  for (int v = tid; v < 1024; v += 256) {
    int o = v >> 5, s = v & 31;
    float acc = b1[o];
#pragma unroll
    for (int c = 0; c < 32; ++c) acc = fmaf(w1[o * 32 + c], X2[c * 32 + s], acc);
    Yp[o * 33 + s] = acc;
  }
  __syncthreads();
  accum_stats_pad<32>(Yp, stats, tid, bm);
}

__global__ __launch_bounds__(256) void pass3_rec_kernel(
    const float* __restrict__ X1g, const float* __restrict__ feat,
    const int* __restrict__ idx_buf,
    const float* __restrict__ w0, const float* __restrict__ b0,
    const float* __restrict__ mur1, const float* __restrict__ g0, const float* __restrict__ be0,
    const float* __restrict__ w1, const float* __restrict__ b1,
    const float* __restrict__ mur2, const float* __restrict__ g1, const float* __restrict__ be1,
    const float* __restrict__ w2, const float* __restrict__ b2,
    float* __restrict__ mm3, double* __restrict__ stats, int big) {
  __shared__ int idxs[NS];
  __shared__ float X1[512];
  __shared__ float X2[1024];
  __shared__ float X3[1024];
  __shared__ float Yp[64 * 33];
  int bm = blockIdx.x, tid = threadIdx.x, b = bm >> 10;
  load_x1(big, X1g, feat, idx_buf, bm, b, tid, idxs, X1);
  __syncthreads();
  for (int v = tid; v < 1024; v += 256) {
    int o = v >> 5, s = v & 31;
    float acc = b0[o];
#pragma unroll
    for (int c = 0; c < 16; ++c) acc = fmaf(w0[o * 16 + c], X1[c * 32 + s], acc);
    X2[v] = bn_relu(acc, mur1[o], mur1[32 + o], g0[o], be0[o]);
  }
  __syncthreads();
  for (int v = tid; v < 1024; v += 256) {
    int o = v >> 5, s = v & 31;
    float acc = b1[o];
#pragma unroll
    for (int c = 0; c < 32; ++c) acc = fmaf(w1[o * 32 + c], X2[c * 32 + s], acc);
    X3[v] = bn_relu(acc, mur2[o], mur2[32 + o], g1[o], be1[o]);
  }
  __syncthreads();
  for (int v = tid; v < 2048; v += 256) {
    int o = v >> 5, s = v & 31;
    float acc = b2[o];
#pragma unroll
    for (int c = 0; c < 32; ++c) acc = fmaf(w2[o * 32 + c], X3[c * 32 + s], acc);
    Yp[o * 33 + s] = acc;
  }
  __syncthreads();
  if (tid < 64) {
    double s1 = 0.0, s2 = 0.0;
    float mx = -3.0e38f, mn = 3.0e38f;
#pragma unroll
    for (int s = 0; s < NS; ++s) {
      float y = Yp[tid * 33 + s];
      double v = (double)y;
      s1 += v; s2 += v * v;
      mx = fmaxf(mx, y); mn = fminf(mn, y);
    }
    double* base = stats + (size_t)(bm & (NR - 1)) * 128;
    atomicAdd(base + tid, s1);
    atomicAdd(base + 64 + tid, s2);
    mm3[bm * 128 + tid * 2] = mx;
    mm3[bm * 128 + tid * 2 + 1] = mn;
  }
}

template <int CO>
__global__ void fixup_mur_kernel(const double* __restrict__ S, float* __restrict__ mur) {
  int o = threadIdx.x;
  if (o >= CO) return;
  double s1 = 0.0, s2 = 0.0;
  for (int r = 0; r < NR; ++r) {
    s1 += S[r * 2 * CO + o];
    s2 += S[r * 2 * CO + CO + o];
  }
  const double P = (double)P_TOT;
  double mu = s1 / P;
  double var = s2 / P - mu * mu;
  mur[o] = (float)mu;
  mur[CO + o] = (float)(1.0 / sqrt(var + 1e-5));
}

extern "C" void kernel_launch(void* const* d_in, const int* in_sizes, int n_in,
                              void* d_out, int out_size, void* d_ws, size_t ws_size,
                              hipStream_t stream) {
  (void)in_sizes; (void)n_in; (void)out_size;
  const float* theta = (const float*)d_in[0];
  const float* phi   = (const float*)d_in[1];
  const float* feat  = (const float*)d_in[2];
  const float* w0 = (const float*)d_in[3];
  const float* b0 = (const float*)d_in[4];
  const float* g0 = (const float*)d_in[5];
  const float* be0 = (const float*)d_in[6];
  const float* w1 = (const float*)d_in[7];
  const float* b1 = (const float*)d_in[8];
  const float* g1 = (const float*)d_in[9];
  const float* be1 = (const float*)d_in[10];
  const float* w2 = (const float*)d_in[11];
  const float* b2 = (const float*)d_in[12];
  const float* g2 = (const float*)d_in[13];
  const float* be2 = (const float*)d_in[14];

  float* out = (float*)d_out;
  float* out_ct = out;
  float* out_cp = out + B_SZ * M_CENT;
  float* out_ft = out + 2 * B_SZ * M_CENT;

  char* ws = (char*)d_ws;
  uint32_t* bits1 = (uint32_t*)(ws + 0);
  uint32_t* bits2 = (uint32_t*)(ws + 131072);
  int* rank2 = (int*)(ws + 262144);
  int* xmid  = (int*)(ws + 393216);
  int* xfin  = (int*)(ws + 524288);      // xfin[0:1024] == cent_idx
  int* idx_buf = (int*)(ws + 655360);    // [4096][32]
  int* hist1   = (int*)(ws + 1179648);
  int* hist2   = (int*)(ws + 1441792);
  int* prefix1 = (int*)(ws + 1703936);
  int* prefix2 = (int*)(ws + 1966080);
  int* cursor1 = (int*)(ws + 2228224);
  int* cursor2 = (int*)(ws + 2490368);
  int* sorted1 = (int*)(ws + 2752512);
  int* sorted2 = (int*)(ws + 2883584);
  int* gbase1  = (int*)(ws + 3014656);
  int* gbase2  = (int*)(ws + 3015680);
  int* cellcnt = (int*)(ws + 3016704);
  int* cellpre = (int*)(ws + 3049472);
  int* cellcur = (int*)(ws + 3082240);
  float* px    = (float*)(ws + 3115008);
  float* py    = (float*)(ws + 3639296);
  int* pid     = (int*)(ws + 4163584);
  double* stats1 = (double*)(ws + 4687872);   // 32 KB
  double* stats2 = (double*)(ws + 4720640);   // 32 KB
  double* stats3 = (double*)(ws + 4753408);   // 64 KB
  float* mur1 = (float*)(ws + 4818944);
  float* mur2 = (float*)(ws + 4819200);
  float* mur3 = (float*)(ws + 4819456);
  float* mm3  = (float*)(ws + 4820480);       // 4096*128*4 = 2 MB
  float* stash = (float*)(ws + 6917632);      // Y1g 16MB | X1g 8MB (fallback)
  float* Y2g  = (float*)(ws + 23694848);      // 16 MB, ends 40472064
  size_t NEED_FULL = (size_t)40472064;
  size_t NEED_BIG  = (size_t)6917632 + 8388608;
  int full = (ws_size >= NEED_FULL) ? 1 : 0;
  int big  = (!full && ws_size >= NEED_BIG) ? 1 : 0;

  hipMemsetAsync(hist1, 0, 524288, stream);        // hist1 + hist2
  hipMemsetAsync(cellcnt, 0, 32768, stream);
  hipMemsetAsync(stats1, 0, 131072, stream);       // stats1..3

  perm_bits_kernel<<<128, 256, 0, stream>>>(bits1, bits2);
  hist_kernel<<<128, 256, 0, stream>>>(bits1, bits2, hist1, hist2);
  gsum_scan_kernel<<<2, 256, 0, stream>>>(hist1, hist2, gbase1, gbase2);
  bucket_scan_kernel<<<dim3(256, 2), 256, 0, stream>>>(hist1, hist2, gbase1, gbase2,
                                                       prefix1, prefix2, cursor1, cursor2);
  bucket_scatter_kernel<<<128, 256, 0, stream>>>(bits1, bits2, cursor1, cursor2,
                                                 sorted1, sorted2);
  rank_scatter1_kernel<<<128, 256, 0, stream>>>(bits1, bits2, prefix1, prefix2,
                                                hist1, hist2, sorted1, sorted2,
                                                xmid, rank2);
  scatter2_kernel<<<128, 256, 0, stream>>>(rank2, xmid, xfin);

  cell_hist_kernel<<<512, 256, 0, stream>>>(theta, phi, cellcnt);
  cell_scan_kernel<<<4, 256, 0, stream>>>(cellcnt, cellpre, cellcur);
  cell_scatter_kernel<<<512, 256, 0, stream>>>(theta, phi, cellcur, px, py, pid);

  select_kernel<<<1024, 256, 0, stream>>>(theta, phi, xfin, cellpre, cellcnt,
                                          px, py, pid, idx_buf, out_ct, out_cp);

  int mode = full ? 2 : (big ? 1 : 0);
  pass1_kernel<<<4096, 256, 0, stream>>>(feat, idx_buf, w0, b0, stash, stats1, mode);
  fixup_mur_kernel<32><<<1, 64, 0, stream>>>(stats1, mur1);
  if (full) {
    pass2s_kernel<<<4096, 256, 0, stream>>>(stash, mur1, g0, be0, w1, b1, Y2g, stats2);
    fixup_mur_kernel<32><<<1, 64, 0, stream>>>(stats2, mur2);
    pass3s_kernel<<<4096, 256, 0, stream>>>(Y2g, mur2, g1, be1, w2, b2, mm3, stats3);
  } else {
    pass2_rec_kernel<<<4096, 256, 0, stream>>>(stash, feat, idx_buf, w0, b0, mur1, g0, be0,
                                               w1, b1, stats2, big);
    fixup_mur_kernel<32><<<1, 64, 0, stream>>>(stats2, mur2);
    pass3_rec_kernel<<<4096, 256, 0, stream>>>(stash, feat, idx_buf, w0, b0, mur1, g0, be0,
                                               w1, b1, mur2, g1, be1, w2, b2, mm3, stats3, big);
  }
  fixup_mur_kernel<64><<<1, 64, 0, stream>>>(stats3, mur3);
  final_small_kernel<<<1024, 256, 0, stream>>>(mm3, mur3, g2, be2, out_ft);
}

// Round 10
// 276.961 us; speedup vs baseline: 3.3980x; 1.0435x over previous
//
#include <hip/hip_runtime.h>
#include <stdint.h>

#define N_PTS 32768
#define M_CENT 1024
#define B_SZ 4
#define NS 32
#define NR 64
#define P_TOT (B_SZ * NS * M_CENT) /* 131072 */

// spatial grid: cell 0.11 > radius 0.1 => +/-1-cell window provably covers
#define GT 29
#define GP 58
#define NCELL (GT * GP) /* 1682 */
#define INVF (1.0f / 0.11f)
#define CAPW 320

__device__ __forceinline__ int cell_t(float t) {
  return min(GT - 1, (int)(t * INVF));
}
__device__ __forceinline__ int cell_p(float p) {
  return min(GP - 1, (int)(p * INVF));
}

// ---------------- threefry2x32 (JAX partitionable mode) ----------------
struct Key2 { uint32_t a, b; };

__device__ __forceinline__ uint32_t rotl32(uint32_t v, uint32_t r) {
  return (v << r) | (v >> (32u - r));
}

__device__ __forceinline__ void tf2x32(uint32_t k0, uint32_t k1,
                                       uint32_t& x0, uint32_t& x1) {
  uint32_t ks0 = k0, ks1 = k1, ks2 = k0 ^ k1 ^ 0x1BD11BDAu;
  x0 += ks0; x1 += ks1;
#define TF_ROUND(r) { x0 += x1; x1 = rotl32(x1, r); x1 ^= x0; }
  TF_ROUND(13u) TF_ROUND(15u) TF_ROUND(26u) TF_ROUND(6u)
  x0 += ks1; x1 += ks2 + 1u;
  TF_ROUND(17u) TF_ROUND(29u) TF_ROUND(16u) TF_ROUND(24u)
  x0 += ks2; x1 += ks0 + 2u;
  TF_ROUND(13u) TF_ROUND(15u) TF_ROUND(26u) TF_ROUND(6u)
  x0 += ks0; x1 += ks1 + 3u;
  TF_ROUND(17u) TF_ROUND(29u) TF_ROUND(16u) TF_ROUND(24u)
  x0 += ks1; x1 += ks2 + 4u;
  TF_ROUND(13u) TF_ROUND(15u) TF_ROUND(26u) TF_ROUND(6u)
  x0 += ks2; x1 += ks0 + 5u;
#undef TF_ROUND
}

__device__ __forceinline__ Key2 tf_block(Key2 k, uint32_t hi, uint32_t lo) {
  uint32_t x0 = hi, x1 = lo;
  tf2x32(k.a, k.b, x0, x1);
  Key2 r; r.a = x0; r.b = x1; return r;
}

// -------- prep: perm bits + bucket hist (j<32768) and cell hist (all j) --------
__global__ __launch_bounds__(256) void prep_kernel(const float* __restrict__ theta,
                                                   const float* __restrict__ phi,
                                                   uint32_t* __restrict__ bits1,
                                                   uint32_t* __restrict__ bits2,
                                                   int* __restrict__ hist1,
                                                   int* __restrict__ hist2,
                                                   int* __restrict__ cellcnt) {
  int j = blockIdx.x * 256 + threadIdx.x;        // 0 .. 131071
  int b = j >> 15;
  float t = theta[j], p = phi[j];
  atomicAdd(&cellcnt[b * NCELL + cell_t(t) * GP + cell_p(p)], 1);
  if (j < N_PTS) {
    Key2 root; root.a = 0u; root.b = 42u;        // jax.random.key(42)
    Key2 k1   = tf_block(root, 0u, 0u);          // split(key)[0] -> permutation key
    Key2 keyA = tf_block(k1, 0u, 0u);
    Key2 sub1 = tf_block(k1, 0u, 1u);
    Key2 sub2 = tf_block(keyA, 0u, 1u);
    Key2 r1 = tf_block(sub1, 0u, (uint32_t)j);
    Key2 r2 = tf_block(sub2, 0u, (uint32_t)j);
    uint32_t v1 = r1.a ^ r1.b, v2 = r2.a ^ r2.b;
    bits1[j] = v1; bits2[j] = v2;
    atomicAdd(&hist1[v1 >> 16], 1);
    atomicAdd(&hist2[v2 >> 16], 1);
  }
}

// -------- feat transpose: [B][16][N] -> [B][N][16] (coalesced both sides) --------
__global__ __launch_bounds__(256) void transpose_kernel(const float* __restrict__ feat,
                                                        float* __restrict__ featT) {
  __shared__ float lds[16][65];                  // 65: conflict-free both phases
  int b = blockIdx.y;
  int n0 = blockIdx.x * 64;
  int tid = threadIdx.x;
#pragma unroll
  for (int k = 0; k < 4; ++k) {
    int v = tid + k * 256;                       // 0..1023
    int c = v >> 6, no = v & 63;
    lds[c][no] = feat[((size_t)(b * 16 + c) << 15) + n0 + no];
  }
  __syncthreads();
#pragma unroll
  for (int k = 0; k < 4; ++k) {
    int v = tid + k * 256;
    int no = v >> 4, c = v & 15;
    featT[((size_t)(b << 15) + n0 + no) * 16 + c] = lds[c][no];
  }
}

// -------- fused scans: blocks 0-1 = bucket group sums; blocks 2-5 = cell scans --------
__global__ __launch_bounds__(256) void scans_kernel(const int* __restrict__ hist1,
                                                    const int* __restrict__ hist2,
                                                    int* __restrict__ gbase1,
                                                    int* __restrict__ gbase2,
                                                    const int* __restrict__ cellcnt,
                                                    int* __restrict__ cellpre,
                                                    int* __restrict__ cellcur) {
  __shared__ int s[256];
  int t = threadIdx.x;
  if (blockIdx.x < 2) {
    const int* hist = blockIdx.x == 0 ? hist1 : hist2;
    int* gbase = blockIdx.x == 0 ? gbase1 : gbase2;
    int sum = 0;
    for (int i = 0; i < 256; ++i) sum += hist[t * 256 + i];
    s[t] = sum;
    __syncthreads();
    if (t == 0) {
      int run = 0;
      for (int i = 0; i < 256; ++i) { int v = s[i]; s[i] = run; run += v; }
    }
    __syncthreads();
    gbase[t] = s[t];
  } else {
    int b = blockIdx.x - 2;
    const int* cnt = cellcnt + b * NCELL;
    int i0 = t * 7, i1 = min(i0 + 7, NCELL);
    int sum = 0;
    for (int i = i0; i < i1; ++i) sum += cnt[i];
    s[t] = sum;
    __syncthreads();
    for (int off = 1; off < 256; off <<= 1) {
      int v = (t >= off) ? s[t - off] : 0;
      __syncthreads();
      s[t] += v;
      __syncthreads();
    }
    int run = (t == 0) ? 0 : s[t - 1];
    for (int i = i0; i < i1; ++i) {
      cellpre[b * NCELL + i] = run;
      cellcur[b * NCELL + i] = run;
      run += cnt[i];
    }
  }
}

__global__ __launch_bounds__(256) void bucket_scan_kernel(const int* __restrict__ hist1,
                                                          const int* __restrict__ hist2,
                                                          const int* __restrict__ gbase1,
                                                          const int* __restrict__ gbase2,
                                                          int* __restrict__ prefix1,
                                                          int* __restrict__ prefix2,
                                                          int* __restrict__ cursor1,
                                                          int* __restrict__ cursor2) {
  __shared__ int s[256];
  const int* hist = blockIdx.y == 0 ? hist1 : hist2;
  const int* gbase = blockIdx.y == 0 ? gbase1 : gbase2;
  int* prefix = blockIdx.y == 0 ? prefix1 : prefix2;
  int* cursor = blockIdx.y == 0 ? cursor1 : cursor2;
  int g = blockIdx.x, t = threadIdx.x;
  int idx = g * 256 + t;
  int orig = hist[idx];
  s[t] = orig;
  __syncthreads();
  for (int off = 1; off < 256; off <<= 1) {
    int v = (t >= off) ? s[t - off] : 0;
    __syncthreads();
    s[t] += v;
    __syncthreads();
  }
  int pref = gbase[g] + s[t] - orig;
  prefix[idx] = pref;
  cursor[idx] = pref;
}

// -------- fused scatters: cell scatter (all j, packed float4) + bucket scatter (j<32768) --------
__global__ __launch_bounds__(256) void scatter_kernel(const float* __restrict__ theta,
                                                      const float* __restrict__ phi,
                                                      int* __restrict__ cellcur,
                                                      float4* __restrict__ pts4,
                                                      const uint32_t* __restrict__ bits1,
                                                      const uint32_t* __restrict__ bits2,
                                                      int* __restrict__ cursor1,
                                                      int* __restrict__ cursor2,
                                                      int* __restrict__ sorted1,
                                                      int* __restrict__ sorted2) {
  int j = blockIdx.x * 256 + threadIdx.x;
  int b = j >> 15, n = j & (N_PTS - 1);
  float t = theta[j], p = phi[j];
  int cell = b * NCELL + cell_t(t) * GP + cell_p(p);
  int pos = atomicAdd(&cellcur[cell], 1);
  pts4[(b << 15) + pos] = make_float4(t, p, __int_as_float(n), 0.0f);
  if (j < N_PTS) {
    int p1 = atomicAdd(&cursor1[bits1[j] >> 16], 1);
    sorted1[p1] = j;
    int p2 = atomicAdd(&cursor2[bits2[j] >> 16], 1);
    sorted2[p2] = j;
  }
}

__device__ __forceinline__ int exact_rank(const uint32_t* __restrict__ bits,
                                          const int* __restrict__ prefix,
                                          const int* __restrict__ hist,
                                          const int* __restrict__ sorted, int j) {
  uint32_t my = bits[j];
  int b = (int)(my >> 16);
  int start = prefix[b];
  int cnt = hist[b];
  int r = start;
  for (int i = 0; i < cnt; ++i) {
    int m = sorted[start + i];
    uint32_t vb = bits[m];
    if (vb < my || (vb == my && m < j)) ++r;
  }
  return r;
}

__global__ __launch_bounds__(256) void rank_scatter1_kernel(
    const uint32_t* __restrict__ bits1, const uint32_t* __restrict__ bits2,
    const int* __restrict__ prefix1, const int* __restrict__ prefix2,
    const int* __restrict__ hist1, const int* __restrict__ hist2,
    const int* __restrict__ sorted1, const int* __restrict__ sorted2,
    int* __restrict__ xmid, int* __restrict__ rank2) {
  int j = blockIdx.x * 256 + threadIdx.x;
  int r1 = exact_rank(bits1, prefix1, hist1, sorted1, j);
  xmid[r1] = j;
  rank2[j] = exact_rank(bits2, prefix2, hist2, sorted2, j);
}

__global__ __launch_bounds__(256) void scatter2_kernel(const int* __restrict__ rank2,
                                                       const int* __restrict__ xmid,
                                                       int* __restrict__ xfin) {
  int p = blockIdx.x * 256 + threadIdx.x;
  xfin[rank2[p]] = xmid[p];
}

// -------- neighbor selection: one WAVE per center (4 waves/block) --------
__global__ __launch_bounds__(256) void select_kernel(
    const float* __restrict__ theta, const float* __restrict__ phi,
    const int* __restrict__ cent,
    const int* __restrict__ cellpre, const int* __restrict__ cellcnt,
    const float4* __restrict__ pts4,
    int* __restrict__ idx_buf, float* __restrict__ out_ct, float* __restrict__ out_cp) {
  __shared__ float wsc[4][CAPW];
  __shared__ int wsn[4][CAPW];
  int tid = threadIdx.x;
  int w = tid >> 6, lane = tid & 63;
  int bm = blockIdx.x * 4 + w;
  int b = bm >> 10, m = bm & 1023;
  int ci = cent[m];
  float ctv = theta[(b << 15) + ci];
  float cpv = phi[(b << 15) + ci];
  if (lane == 0) { out_ct[bm] = ctv; out_cp[bm] = cpv; }

  Key2 root; root.a = 0u; root.b = 42u;
  Key2 k2 = tf_block(root, 0u, 1u);              // split(key)[1] -> scores key
  uint32_t flat_base = (uint32_t)bm << 15;

  int tc = cell_t(ctv), pc = cell_p(cpv);
  int t0 = max(0, tc - 1), t1 = min(GT - 1, tc + 1);
  int p0 = max(0, pc - 1), p1 = min(GP - 1, pc + 1);
  int nct = t1 - t0 + 1, ncp = p1 - p0 + 1, ncells = nct * ncp;

  // lane < ncells loads its cell descriptor; broadcast all to the wave
  int cst = 0, ccn = 0;
  if (lane < ncells) {
    int cell = b * NCELL + (t0 + lane / ncp) * GP + (p0 + lane % ncp);
    cst = cellpre[cell];
    ccn = cellcnt[cell];
  }
  int sc9[9], cc9[9];
#pragma unroll
  for (int k = 0; k < 9; ++k) {
    sc9[k] = __shfl(cst, k);
    cc9[k] = __shfl(ccn, k);
  }
  int T = 0;
#pragma unroll
  for (int k = 0; k < 9; ++k) T += cc9[k];

  const float4* bpts = pts4 + ((size_t)b << 15);
  int wcnt = 0;
  for (int base = 0; base < T; base += 64) {
    int i = base + lane;
    bool hit = false; float sc = 0.0f; int n = 0;
    if (i < T) {
      int gidx = 0, acc = 0;
#pragma unroll
      for (int k = 0; k < 9; ++k) {
        int lo = acc; acc += cc9[k];
        if (i >= lo && i < acc) gidx = sc9[k] + (i - lo);
      }
      float4 pt = bpts[gidx];
      // match XLA's uncontracted f32 elementwise chain exactly
      float dx = __fsub_rn(pt.x, ctv);
      float dy = __fsub_rn(pt.y, cpv);
      float d = __fsqrt_rn(__fadd_rn(__fmul_rn(dx, dx), __fmul_rn(dy, dy)));
      if (d <= 0.1f) {
        hit = true; n = __float_as_int(pt.z);
        Key2 r = tf_block(k2, 0u, flat_base + (uint32_t)n);
        uint32_t bits = r.a ^ r.b;
        sc = __uint_as_float(0x3f800000u | (bits >> 9)) - 1.0f; // uniform [0,1)
      }
    }
    unsigned long long mask = __ballot(hit);
    int pos = wcnt + __popcll(mask & ((1ull << lane) - 1ull));
    if (hit && pos < CAPW) { wsc[w][pos] = sc; wsn[w][pos] = n; }
    wcnt = min(wcnt + (int)__popcll(mask), CAPW);
  }

  int mysel;
  if (wcnt <= 64) {
    // FAST PATH: 64-lane bitonic sort by lex (score, n) ascending.
    // Total order (n unique) => identical picks to stable top_k.
    float s = (lane < wcnt) ? wsc[w][lane] : 3.0e38f;
    int n = (lane < wcnt) ? wsn[w][lane] : 0x7fffffff;
#pragma unroll
    for (int k = 2; k <= 64; k <<= 1) {
#pragma unroll
      for (int jj = k >> 1; jj > 0; jj >>= 1) {
        float os = __shfl_xor(s, jj);
        int on = __shfl_xor(n, jj);
        bool lower = (lane & jj) == 0;
        bool dir = (lane & k) == 0;
        bool mineFirst = (s < os) || (s == os && n < on);
        bool takeMine = ((lower == mineFirst) == dir);
        s = takeMine ? s : os;
        n = takeMine ? n : on;
      }
    }
    int n0 = __shfl(n, 0);                        // argmin -> pad value
    mysel = (lane < wcnt) ? n : n0;
  } else {
    // SLOW PATH (wcnt>64, ~5%): 32 rounds of lex-min strictly after last pick
    float ls = -1.0f; int ln = -1;
    int sel0 = -1; mysel = -1;
    for (int r = 0; r < NS; ++r) {
      float best = 3.0e38f; int bn = 0x7fffffff;
      for (int i = lane; i < wcnt; i += 64) {
        float s = wsc[w][i]; int n = wsn[w][i];
        bool after = (s > ls) || (s == ls && n > ln);
        bool better = (s < best) || (s == best && n < bn);
        if (after && better) { best = s; bn = n; }
      }
      for (int off = 32; off; off >>= 1) {
        float os = __shfl_xor(best, off);
        int on = __shfl_xor(bn, off);
        if (os < best || (os == best && on < bn)) { best = os; bn = on; }
      }
      int chosen;
      if (best < 3.0e38f) { ls = best; ln = bn; chosen = bn; }
      else chosen = sel0;
      if (r == 0) sel0 = chosen;
      if (lane == r) mysel = chosen;
    }
  }
  if (lane < NS) idx_buf[bm * NS + lane] = mysel;
}

// -------- MLP --------
__device__ __forceinline__ float bn_relu(float y, float mu, float r, float g, float be) {
  float t = __fsub_rn(y, mu);
  t = __fmul_rn(t, r);
  t = __fmul_rn(t, g);
  t = __fadd_rn(t, be);
  return fmaxf(t, 0.0f);
}

template <int CO>
__device__ __forceinline__ void accum_stats_pad(const float* __restrict__ Yp,
                                                double* __restrict__ S, int tid, int bid) {
  if (tid < CO) {
    double s1 = 0.0, s2 = 0.0;
#pragma unroll
    for (int s = 0; s < NS; ++s) {
      double v = (double)Yp[tid * 33 + s];
      s1 += v; s2 += v * v;
    }
    double* base = S + (size_t)(bid & (NR - 1)) * (2 * CO);
    atomicAdd(base + tid, s1);
    atomicAdd(base + CO + tid, s2);
  }
}

// pass1: gather + L1 -> stash (mode>=2: Y1; mode1: X1) ; stats1
// mode3: gather via featT (4x float4 per point), else channel-major scatter loads
__global__ __launch_bounds__(256) void pass1_kernel(
    const float* __restrict__ feat, const float* __restrict__ featT,
    const int* __restrict__ idx_buf,
    const float* __restrict__ w0, const float* __restrict__ b0,
    float* __restrict__ stash, double* __restrict__ stats, int mode) {
  __shared__ int idxs[NS];
  __shared__ float X1[512];
  __shared__ float Yp[32 * 33];
  int bm = blockIdx.x, tid = threadIdx.x, b = bm >> 10;
  if (tid < NS) idxs[tid] = idx_buf[bm * NS + tid];
  __syncthreads();
  if (mode == 3) {
    if (tid < 128) {
      int s = tid >> 2, c4 = tid & 3;
      float4 f = *reinterpret_cast<const float4*>(
          &featT[((size_t)(b << 15) + idxs[s]) * 16 + c4 * 4]);
      X1[(c4 * 4 + 0) * 32 + s] = f.x;
      X1[(c4 * 4 + 1) * 32 + s] = f.y;
      X1[(c4 * 4 + 2) * 32 + s] = f.z;
      X1[(c4 * 4 + 3) * 32 + s] = f.w;
    }
  } else {
    for (int v = tid; v < 512; v += 256) {
      int c = v >> 5, s = v & 31;
      float val = feat[(size_t)(b * 16 + c) * N_PTS + idxs[s]];
      X1[v] = val;
      if (mode == 1) stash[(size_t)bm * 512 + v] = val;
    }
  }
  __syncthreads();
  for (int v = tid; v < 1024; v += 256) {
    int o = v >> 5, s = v & 31;
    float acc = b0[o];
#pragma unroll
    for (int c = 0; c < 16; ++c) acc = fmaf(w0[o * 16 + c], X1[c * 32 + s], acc);
    Yp[o * 33 + s] = acc;
    if (mode >= 2) stash[(size_t)bm * 1024 + v] = acc;
  }
  __syncthreads();
  accum_stats_pad<32>(Yp, stats, tid, bm);
}

// pass2s: read Y1g, bn1+relu, L2 -> stats2 only (Y2 recomputed in pass3s)
__global__ __launch_bounds__(256) void pass2s_kernel(
    const float* __restrict__ Y1g,
    const float* __restrict__ mur1, const float* __restrict__ g0, const float* __restrict__ be0,
    const float* __restrict__ w1, const float* __restrict__ b1,
    double* __restrict__ stats) {
  __shared__ float X2[1024];
  __shared__ float Yp[32 * 33];
  int bm = blockIdx.x, tid = threadIdx.x;
  for (int v = tid; v < 1024; v += 256) {
    int o = v >> 5;
    X2[v] = bn_relu(Y1g[(size_t)bm * 1024 + v], mur1[o], mur1[32 + o], g0[o], be0[o]);
  }
  __syncthreads();
  for (int v = tid; v < 1024; v += 256) {
    int o = v >> 5, s = v & 31;
    float acc = b1[o];
#pragma unroll
    for (int c = 0; c < 32; ++c) acc = fmaf(w1[o * 32 + c], X2[c * 32 + s], acc);
    Yp[o * 33 + s] = acc;
  }
  __syncthreads();
  accum_stats_pad<32>(Yp, stats, tid, bm);
}

// pass3s: read Y1g, recompute L2 (bit-identical), bn2+relu, L3 ; stats3 + min/max
__global__ __launch_bounds__(256) void pass3s_kernel(
    const float* __restrict__ Y1g,
    const float* __restrict__ mur1, const float* __restrict__ g0, const float* __restrict__ be0,
    const float* __restrict__ w1, const float* __restrict__ b1,
    const float* __restrict__ mur2, const float* __restrict__ g1, const float* __restrict__ be1,
    const float* __restrict__ w2, const float* __restrict__ b2,
    float* __restrict__ mm3, double* __restrict__ stats) {
  __shared__ float X2[1024];
  __shared__ float X3[1024];
  __shared__ float Yp[64 * 33];
  int bm = blockIdx.x, tid = threadIdx.x;
  for (int v = tid; v < 1024; v += 256) {
    int o = v >> 5;
    X2[v] = bn_relu(Y1g[(size_t)bm * 1024 + v], mur1[o], mur1[32 + o], g0[o], be0[o]);
  }
  __syncthreads();
  for (int v = tid; v < 1024; v += 256) {
    int o = v >> 5, s = v & 31;
    float acc = b1[o];
#pragma unroll
    for (int c = 0; c < 32; ++c) acc = fmaf(w1[o * 32 + c], X2[c * 32 + s], acc);
    X3[v] = bn_relu(acc, mur2[o], mur2[32 + o], g1[o], be1[o]);
  }
  __syncthreads();
  for (int v = tid; v < 2048; v += 256) {
    int o = v >> 5, s = v & 31;
    float acc = b2[o];
#pragma unroll
    for (int c = 0; c < 32; ++c) acc = fmaf(w2[o * 32 + c], X3[c * 32 + s], acc);
    Yp[o * 33 + s] = acc;
  }
  __syncthreads();
  if (tid < 64) {
    double s1 = 0.0, s2 = 0.0;
    float mx = -3.0e38f, mn = 3.0e38f;
#pragma unroll
    for (int s = 0; s < NS; ++s) {
      float y = Yp[tid * 33 + s];
      double v = (double)y;
      s1 += v; s2 += v * v;
      mx = fmaxf(mx, y); mn = fminf(mn, y);
    }
    double* base = stats + (size_t)(bm & (NR - 1)) * 128;
    atomicAdd(base + tid, s1);
    atomicAdd(base + 64 + tid, s2);
    mm3[bm * 128 + tid * 2] = mx;
    mm3[bm * 128 + tid * 2 + 1] = mn;
  }
}

// final: BN3 on the extremum; exact because bn_relu is weakly monotone in y
__global__ __launch_bounds__(256) void final_small_kernel(
    const float* __restrict__ mm3,
    const float* __restrict__ mur3, const float* __restrict__ g2, const float* __restrict__ be2,
    float* __restrict__ out_ft) {
  int j = blockIdx.x * 256 + threadIdx.x;          // (b*64+o)*1024+m
  int b = j >> 16, o = (j >> 10) & 63, m = j & 1023;
  int bm = b * 1024 + m;
  float g = g2[o];
  float y = (g >= 0.0f) ? mm3[bm * 128 + o * 2] : mm3[bm * 128 + o * 2 + 1];
  out_ft[j] = bn_relu(y, mur3[o], mur3[64 + o], g, be2[o]);
}

// -------- fallback recompute kernels (ws too small) --------
__device__ __forceinline__ void load_x1(int big, const float* __restrict__ X1g,
                                        const float* __restrict__ feat,
                                        const int* __restrict__ idx_buf,
                                        int bm, int b, int tid,
                                        int* idxs, float* X1) {
  if (!big) {
    if (tid < NS) idxs[tid] = idx_buf[bm * NS + tid];
  }
  __syncthreads();
  if (big) {
    for (int v = tid; v < 512; v += 256) X1[v] = X1g[(size_t)bm * 512 + v];
  } else {
    for (int v = tid; v < 512; v += 256) {
      int c = v >> 5, s = v & 31;
      X1[v] = feat[(size_t)(b * 16 + c) * N_PTS + idxs[s]];
    }
  }
}

__global__ __launch_bounds__(256) void pass2_rec_kernel(
    const float* __restrict__ X1g, const float* __restrict__ feat,
    const int* __restrict__ idx_buf,
    const float* __restrict__ w0, const float* __restrict__ b0,
    const float* __restrict__ mur1, const float* __restrict__ g0, const float* __restrict__ be0,
    const float* __restrict__ w1, const float* __restrict__ b1,
    double* __restrict__ stats, int big) {
  __shared__ int idxs[NS];
  __shared__ float X1[512];
  __shared__ float X2[1024];
  __shared__ float Yp[32 * 33];
  int bm = blockIdx.x, tid = threadIdx.x, b = bm >> 10;
  load_x1(big, X1g, feat, idx_buf, bm, b, tid, idxs, X1);
  __syncthreads();
  for (int v = tid; v < 1024; v += 256) {
    int o = v >> 5, s = v & 31;
    float acc = b0[o];
#pragma unroll
    for (int c = 0; c < 16; ++c) acc = fmaf(w0[o * 16 + c], X1[c * 32 + s], acc);
    X2[v] = bn_relu(acc, mur1[o], mur1[32 + o], g0[o], be0[o]);
  }
  __syncthreads();
  for (int v = tid; v < 1024; v += 256) {
    int o = v >> 5, s = v & 31;
    float acc = b1[o];
#pragma unroll
    for (int c = 0; c < 32; ++c) acc = fmaf(w1[o * 32 + c], X2[c * 32 + s], acc);
    Yp[o * 33 + s] = acc;
  }
  __syncthreads();
  accum_stats_pad<32>(Yp, stats, tid, bm);
}

__global__ __launch_bounds__(256) void pass3_rec_kernel(
    const float* __restrict__ X1g, const float* __restrict__ feat,
    const int* __restrict__ idx_buf,
    const float* __restrict__ w0, const float* __restrict__ b0,
    const float* __restrict__ mur1, const float* __restrict__ g0, const float* __restrict__ be0,
    const float* __restrict__ w1, const float* __restrict__ b1,
    const float* __restrict__ mur2, const float* __restrict__ g1, const float* __restrict__ be1,
    const float* __restrict__ w2, const float* __restrict__ b2,
    float* __restrict__ mm3, double* __restrict__ stats, int big) {
  __shared__ int idxs[NS];
  __shared__ float X1[512];
  __shared__ float X2[1024];
  __shared__ float X3[1024];
  __shared__ float Yp[64 * 33];
  int bm = blockIdx.x, tid = threadIdx.x, b = bm >> 10;
  load_x1(big, X1g, feat, idx_buf, bm, b, tid, idxs, X1);
  __syncthreads();
  for (int v = tid; v < 1024; v += 256) {
    int o = v >> 5, s = v & 31;
    float acc = b0[o];
#pragma unroll
    for (int c = 0; c < 16; ++c) acc = fmaf(w0[o * 16 + c], X1[c * 32 + s], acc);
    X2[v] = bn_relu(acc, mur1[o], mur1[32 + o], g0[o], be0[o]);
  }
  __syncthreads();
  for (int v = tid; v < 1024; v += 256) {
    int o = v >> 5, s = v & 31;
    float acc = b1[o];
#pragma unroll
    for (int c = 0; c < 32; ++c) acc = fmaf(w1[o * 32 + c], X2[c * 32 + s], acc);
    X3[v] = bn_relu(acc, mur2[o], mur2[32 + o], g1[o], be1[o]);
  }
  __syncthreads();
  for (int v = tid; v < 2048; v += 256) {
    int o = v >> 5, s = v & 31;
    float acc = b2[o];
#pragma unroll
    for (int c = 0; c < 32; ++c) acc = fmaf(w2[o * 32 + c], X3[c * 32 + s], acc);
    Yp[o * 33 + s] = acc;
  }
  __syncthreads();
  if (tid < 64) {
    double s1 = 0.0, s2 = 0.0;
    float mx = -3.0e38f, mn = 3.0e38f;
#pragma unroll
    for (int s = 0; s < NS; ++s) {
      float y = Yp[tid * 33 + s];
      double v = (double)y;
      s1 += v; s2 += v * v;
      mx = fmaxf(mx, y); mn = fminf(mn, y);
    }
    double* base = stats + (size_t)(bm & (NR - 1)) * 128;
    atomicAdd(base + tid, s1);
    atomicAdd(base + 64 + tid, s2);
    mm3[bm * 128 + tid * 2] = mx;
    mm3[bm * 128 + tid * 2 + 1] = mn;
  }
}

template <int CO>
__global__ void fixup_mur_kernel(const double* __restrict__ S, float* __restrict__ mur) {
  int o = threadIdx.x;
  if (o >= CO) return;
  double s1 = 0.0, s2 = 0.0;
  for (int r = 0; r < NR; ++r) {
    s1 += S[r * 2 * CO + o];
    s2 += S[r * 2 * CO + CO + o];
  }
  const double P = (double)P_TOT;
  double mu = s1 / P;
  double var = s2 / P - mu * mu;
  mur[o] = (float)mu;
  mur[CO + o] = (float)(1.0 / sqrt(var + 1e-5));
}

extern "C" void kernel_launch(void* const* d_in, const int* in_sizes, int n_in,
                              void* d_out, int out_size, void* d_ws, size_t ws_size,
                              hipStream_t stream) {
  (void)in_sizes; (void)n_in; (void)out_size;
  const float* theta = (const float*)d_in[0];
  const float* phi   = (const float*)d_in[1];
  const float* feat  = (const float*)d_in[2];
  const float* w0 = (const float*)d_in[3];
  const float* b0 = (const float*)d_in[4];
  const float* g0 = (const float*)d_in[5];
  const float* be0 = (const float*)d_in[6];
  const float* w1 = (const float*)d_in[7];
  const float* b1 = (const float*)d_in[8];
  const float* g1 = (const float*)d_in[9];
  const float* be1 = (const float*)d_in[10];
  const float* w2 = (const float*)d_in[11];
  const float* b2 = (const float*)d_in[12];
  const float* g2 = (const float*)d_in[13];
  const float* be2 = (const float*)d_in[14];

  float* out = (float*)d_out;
  float* out_ct = out;
  float* out_cp = out + B_SZ * M_CENT;
  float* out_ft = out + 2 * B_SZ * M_CENT;

  char* ws = (char*)d_ws;
  uint32_t* bits1 = (uint32_t*)(ws + 0);          // 128K
  uint32_t* bits2 = (uint32_t*)(ws + 131072);     // 128K
  int* rank2 = (int*)(ws + 262144);               // 128K
  int* xmid  = (int*)(ws + 393216);               // 128K
  int* xfin  = (int*)(ws + 524288);               // 128K; [0:1024] == cent_idx
  int* idx_buf = (int*)(ws + 655360);             // 512K
  // ---- single contiguous memset region [1179648, 1867776) ----
  int* hist1   = (int*)(ws + 1179648);            // 256K
  int* hist2   = (int*)(ws + 1441792);            // 256K
  int* cellcnt = (int*)(ws + 1703936);            // 32K
  double* stats1 = (double*)(ws + 1736704);       // 32K
  double* stats2 = (double*)(ws + 1769472);       // 32K
  double* stats3 = (double*)(ws + 1802240);       // 64K -> end 1867776
  // ----
  int* prefix1 = (int*)(ws + 1867776);            // 256K
  int* prefix2 = (int*)(ws + 2129920);            // 256K
  int* cursor1 = (int*)(ws + 2392064);            // 256K
  int* cursor2 = (int*)(ws + 2654208);            // 256K
  int* sorted1 = (int*)(ws + 2916352);            // 128K
  int* sorted2 = (int*)(ws + 3047424);            // 128K
  int* gbase1  = (int*)(ws + 3178496);            // 1K
  int* gbase2  = (int*)(ws + 3179520);            // 1K
  int* cellpre = (int*)(ws + 3180544);            // 32K
  int* cellcur = (int*)(ws + 3213312);            // 32K
  float4* pts4 = (float4*)(ws + 3246080);         // 2M
  float* mur1 = (float*)(ws + 5343232);
  float* mur2 = (float*)(ws + 5343488);
  float* mur3 = (float*)(ws + 5343744);
  float* mm3  = (float*)(ws + 5344768);           // 2M
  float* stash = (float*)(ws + 7441920);          // Y1g 16M | X1g 8M (fallback)
  float* featT = (float*)(ws + 7441920 + 16777216); // 8M (mode3)
  size_t NEED_FULL = (size_t)7441920 + 16777216;
  size_t NEED_T    = NEED_FULL + 8388608;
  size_t NEED_BIG  = (size_t)7441920 + 8388608;
  int mode = (ws_size >= NEED_T) ? 3
           : (ws_size >= NEED_FULL) ? 2
           : (ws_size >= NEED_BIG) ? 1 : 0;

  hipMemsetAsync(ws + 1179648, 0, 688128, stream);  // hist1,hist2,cellcnt,stats1-3

  prep_kernel<<<512, 256, 0, stream>>>(theta, phi, bits1, bits2, hist1, hist2, cellcnt);
  if (mode == 3)
    transpose_kernel<<<dim3(512, 4), 256, 0, stream>>>(feat, featT);
  scans_kernel<<<6, 256, 0, stream>>>(hist1, hist2, gbase1, gbase2,
                                      cellcnt, cellpre, cellcur);
  bucket_scan_kernel<<<dim3(256, 2), 256, 0, stream>>>(hist1, hist2, gbase1, gbase2,
                                                       prefix1, prefix2, cursor1, cursor2);
  scatter_kernel<<<512, 256, 0, stream>>>(theta, phi, cellcur, pts4,
                                          bits1, bits2, cursor1, cursor2,
                                          sorted1, sorted2);
  rank_scatter1_kernel<<<128, 256, 0, stream>>>(bits1, bits2, prefix1, prefix2,
                                                hist1, hist2, sorted1, sorted2,
                                                xmid, rank2);
  scatter2_kernel<<<128, 256, 0, stream>>>(rank2, xmid, xfin);

  select_kernel<<<1024, 256, 0, stream>>>(theta, phi, xfin, cellpre, cellcnt,
                                          pts4, idx_buf, out_ct, out_cp);

  pass1_kernel<<<4096, 256, 0, stream>>>(feat, featT, idx_buf, w0, b0, stash, stats1, mode);
  fixup_mur_kernel<32><<<1, 64, 0, stream>>>(stats1, mur1);
  if (mode >= 2) {
    pass2s_kernel<<<4096, 256, 0, stream>>>(stash, mur1, g0, be0, w1, b1, stats2);
    fixup_mur_kernel<32><<<1, 64, 0, stream>>>(stats2, mur2);
    pass3s_kernel<<<4096, 256, 0, stream>>>(stash, mur1, g0, be0, w1, b1,
                                            mur2, g1, be1, w2, b2, mm3, stats3);
  } else {
    pass2_rec_kernel<<<4096, 256, 0, stream>>>(stash, feat, idx_buf, w0, b0, mur1, g0, be0,
                                               w1, b1, stats2, mode);
    fixup_mur_kernel<32><<<1, 64, 0, stream>>>(stats2, mur2);
    pass3_rec_kernel<<<4096, 256, 0, stream>>>(stash, feat, idx_buf, w0, b0, mur1, g0, be0,
                                               w1, b1, mur2, g1, be1, w2, b2, mm3, stats3, mode);
  }
  fixup_mur_kernel<64><<<1, 64, 0, stream>>>(stats3, mur3);
  final_small_kernel<<<1024, 256, 0, stream>>>(mm3, mur3, g2, be2, out_ft);
}